// Round 3
// baseline (321.651 us; speedup 1.0000x reference)
//
#include <hip/hip_runtime.h>
#include <hip/hip_bf16.h>
#include <hip/hip_cooperative_groups.h>
#include <math.h>

namespace cg = cooperative_groups;

typedef __hip_bfloat16 bf16;
typedef __attribute__((ext_vector_type(8))) short short8;
typedef __attribute__((ext_vector_type(4))) short sh4;
typedef __attribute__((ext_vector_type(4))) float f32x4;

static __device__ __forceinline__ float bf2f(bf16 h) { return __bfloat162float(h); }
static __device__ __forceinline__ short f2bfs(float f) {
    bf16 h = __float2bfloat16(f);
    return *reinterpret_cast<short*>(&h);
}
static __device__ __forceinline__ short8 cvt8(float4 a, float4 b) {
    short8 o;
    o[0] = f2bfs(a.x); o[1] = f2bfs(a.y); o[2] = f2bfs(a.z); o[3] = f2bfs(a.w);
    o[4] = f2bfs(b.x); o[5] = f2bfs(b.y); o[6] = f2bfs(b.z); o[7] = f2bfs(b.w);
    return o;
}

constexpr int Bn = 8;
constexpr int C  = 256;
constexpr int N  = 1024;     // H*W
constexpr int NH = 8;
constexpr int HD = 32;
constexpr int TS = 264;      // LDS tile stride (shorts)
constexpr float SCALE = 0.17677669529663687f;  // 1/sqrt(32)
// log2(e) folded into the q scale so K2's softmax can use raw v_exp_f32 (2^x)
constexpr float SCALE_E = 0.17677669529663687f * 1.4426950408889634f;

// ===========================================================================
// FUSED cooperative kernel: phase0 weight-cvt | phase1 qkv | phase2 attn |
// phase3 projection, separated by grid.sync(). 512 blocks x 256 thr,
// 2 blocks/CU co-resident (LDS 37.9 KB/block unioned across phases).
// ===========================================================================
__global__ __launch_bounds__(256, 2) void k_all(
    const float* __restrict__ x, const float* __restrict__ gq, const float* __restrict__ gk,
    const float* __restrict__ Wsq, const float* __restrict__ bsq,
    const float* __restrict__ Wsk, const float* __restrict__ bsk,
    const float* __restrict__ Wq, const float* __restrict__ bq,
    const float* __restrict__ Wk, const float* __restrict__ bk,
    const float* __restrict__ Wv, const float* __restrict__ bv,
    const float* __restrict__ Wp, const float* __restrict__ bp,
    bf16* __restrict__ Wb, bf16* __restrict__ qo, bf16* __restrict__ ko,
    bf16* __restrict__ vo, bf16* __restrict__ gt, float* __restrict__ sqg,
    float* __restrict__ out)
{
    __shared__ __align__(16) char smem[37888];
    cg::grid_group grid = cg::this_grid();

    const int tid  = threadIdx.x;
    const int bid  = blockIdx.x;
    const int wave = tid >> 6;
    const int lane = tid & 63;
    const int col  = lane & 15;
    const int quad = lane >> 4;

    // ---------------- phase 0: Wq|Wk|Wv|Wp f32 -> bf16 --------------------
    if (bid < 256) {
        int idx = bid * 256 + tid;            // 65536 float4s total
        int mat = idx >> 14;
        const float* src = (mat == 0) ? Wq : (mat == 1) ? Wk : (mat == 2) ? Wv : Wp;
        float4 v = reinterpret_cast<const float4*>(src)[idx & 16383];
        sh4 o;
        o[0] = f2bfs(v.x); o[1] = f2bfs(v.y); o[2] = f2bfs(v.z); o[3] = f2bfs(v.w);
        reinterpret_cast<sh4*>(reinterpret_cast<short*>(Wb))[idx] = o;
    }
    grid.sync();

    // ---------------- phase 1: transpose + gates + q/k/v GEMM -------------
    {
        short* T      = reinterpret_cast<short*>(smem);          // 64*TS shorts
        float* sq_lds = reinterpret_cast<float*>(smem + 33792);
        float* sk_lds = sq_lds + 64;

        const int b    = bid >> 6;
        const int rest = bid & 63;
        const int n0   = (rest >> 2) * 64;   // 16 tiles of 64 px
        const int mq   = rest & 3;           // m-quarter (192 rows)

        // stage x^T tile: 256 c-rows x 64 pixels
        {
            const float* xp = x + (size_t)b * C * N + n0;
            const int row = tid >> 4;
            const int f   = tid & 15;
#pragma unroll
            for (int p = 0; p < 16; ++p) {
                int c = p * 16 + row;
                float4 v = *reinterpret_cast<const float4*>(xp + (size_t)c * N + f * 4);
                T[(f * 4 + 0) * TS + c] = f2bfs(v.x);
                T[(f * 4 + 1) * TS + c] = f2bfs(v.y);
                T[(f * 4 + 2) * TS + c] = f2bfs(v.z);
                T[(f * 4 + 3) * TS + c] = f2bfs(v.w);
            }
        }
        __syncthreads();

        // gates (wave 0 only)
        if (wave == 0) {
            const float* wsrc = (col < 4) ? (Wsq + col * C) : (Wsk + (col & 3) * C);
            f32x4 ga[4] = {};
#pragma unroll
            for (int k0 = 0; k0 < 256; k0 += 32) {
                float4 w0 = *reinterpret_cast<const float4*>(wsrc + k0 + quad * 8);
                float4 w1 = *reinterpret_cast<const float4*>(wsrc + k0 + quad * 8 + 4);
                short8 af = cvt8(w0, w1);
#pragma unroll
                for (int cf = 0; cf < 4; ++cf) {
                    short8 bfr = *reinterpret_cast<const short8*>(&T[(cf * 16 + col) * TS + k0 + quad * 8]);
                    ga[cf] = __builtin_amdgcn_mfma_f32_16x16x32_bf16(af, bfr, ga[cf], 0, 0, 0);
                }
            }
            if (quad < 2) {
                const float* bsrc = (quad == 0) ? bsq : bsk;
                const float* gsrc = (quad == 0) ? gq : gk;
#pragma unroll
                for (int cf = 0; cf < 4; ++cf) {
                    int n = n0 + cf * 16 + col;
                    float a[4];
#pragma unroll
                    for (int r = 0; r < 4; ++r)
                        a[r] = ga[cf][r] + bsrc[r] + gsrc[(size_t)b * 4 * N + (size_t)r * N + n];
                    float mx = fmaxf(fmaxf(a[0], a[1]), fmaxf(a[2], a[3]));
                    float e = 0.f;
#pragma unroll
                    for (int r = 0; r < 4; ++r) e += __expf(a[r] - mx);
                    float p0 = __expf(a[0] - mx) / e;
                    if (quad == 0) {
                        sq_lds[cf * 16 + col] = p0;
                        if (mq == 0) sqg[b * N + n] = p0;
                    } else {
                        sk_lds[cf * 16 + col] = p0;
                    }
                }
            }
        }
        __syncthreads();

        // GEMM: 192-row M quarter; 3 A-frags x 4 B-frags
        const short* Ws = reinterpret_cast<const short*>(Wb);
        const int mbase = mq * 192 + wave * 48;
        f32x4 acc[3][4] = {};
#pragma unroll
        for (int k0 = 0; k0 < 256; k0 += 32) {
            short8 bfr[4];
#pragma unroll
            for (int cf = 0; cf < 4; ++cf)
                bfr[cf] = *reinterpret_cast<const short8*>(&T[(cf * 16 + col) * TS + k0 + quad * 8]);
#pragma unroll
            for (int i = 0; i < 3; ++i) {
                int m = mbase + i * 16;
                const short* wr = Ws + (size_t)(m >> 8) * 65536
                                  + (size_t)((m & 255) + col) * 256 + k0 + quad * 8;
                short8 af = *reinterpret_cast<const short8*>(wr);
#pragma unroll
                for (int cf = 0; cf < 4; ++cf)
                    acc[i][cf] = __builtin_amdgcn_mfma_f32_16x16x32_bf16(af, bfr[cf], acc[i][cf], 0, 0, 0);
            }
        }
#pragma unroll
        for (int i = 0; i < 3; ++i) {
            int m = mbase + i * 16;
            int mat = m >> 8;
            int cr  = (m & 255) + quad * 4;
            const float* bb = (mat == 0) ? bq : (mat == 1) ? bk : bv;
            float bias[4];
#pragma unroll
            for (int r = 0; r < 4; ++r) bias[r] = bb[cr + r];
            if (mat < 2) {
                short* op = reinterpret_cast<short*>((mat == 0) ? qo : ko) + (size_t)b * N * C;
#pragma unroll
                for (int cf = 0; cf < 4; ++cf) {
                    int n = n0 + cf * 16 + col;
                    float g = (mat == 0) ? sq_lds[cf * 16 + col] * SCALE_E
                                         : sk_lds[cf * 16 + col];
                    sh4 pack;
#pragma unroll
                    for (int r = 0; r < 4; ++r) pack[r] = f2bfs((acc[i][cf][r] + bias[r]) * g);
                    *reinterpret_cast<sh4*>(op + (size_t)n * C + cr) = pack;
                }
            } else {
                bf16* op = vo + (size_t)b * C * N;
#pragma unroll
                for (int cf = 0; cf < 4; ++cf) {
                    int n = n0 + cf * 16 + col;
#pragma unroll
                    for (int r = 0; r < 4; ++r)
                        op[(size_t)(cr + r) * N + n] = __float2bfloat16(acc[i][cf][r] + bias[r]);
                }
            }
        }
    }
    grid.sync();

    // ---------------- phase 2: attention + gated mix (128-q tile) ---------
    {
        short* Pb  = reinterpret_cast<short*>(smem);   // [4][32*72]
        short* Kb0 = Pb + 9216;                        // [2][64*40]
        short* Vb0 = Pb + 14336;                       // [2][32*72]

        const int b = bid >> 6;
        const int h = (bid >> 3) & 7;
        const int qbase = (bid & 7) * 128 + wave * 32;

        const int skey = tid >> 2;          // 0..63
        const int sd   = (tid & 3) * 8;     // 0,8,16,24
        const int svd  = tid >> 3;          // 0..31
        const int svk  = (tid & 7) * 8;     // 0..56

        const short* kgp = reinterpret_cast<const short*>(ko) + (size_t)b * N * C + h * HD;
        const short* vgp = reinterpret_cast<const short*>(vo) + (size_t)b * C * N + (size_t)h * HD * N;
        const short* vp  = vgp;

        short8 qf[2];
        {
            const short* qp = reinterpret_cast<const short*>(qo) + (size_t)b * N * C + h * HD + quad * 8;
#pragma unroll
            for (int g = 0; g < 2; ++g)
                qf[g] = *reinterpret_cast<const short8*>(qp + (size_t)(qbase + g * 16 + col) * C);
        }

        float l[2] = {};
        f32x4 oac[2][2] = {};   // [g][dh]
        short* P = Pb + wave * 2304;

        short8 kstage = *reinterpret_cast<const short8*>(kgp + (size_t)skey * C + sd);
        short8 vstage = *reinterpret_cast<const short8*>(vgp + (size_t)svd * N + svk);
        *reinterpret_cast<short8*>(&Kb0[skey * 40 + sd]) = kstage;
        *reinterpret_cast<short8*>(&Vb0[svd * 72 + svk]) = vstage;
        __syncthreads();

        for (int t = 0; t < 16; ++t) {
            const int tn = (t + 1) & 15;
            kstage = *reinterpret_cast<const short8*>(kgp + (size_t)(tn * 64 + skey) * C + sd);
            vstage = *reinterpret_cast<const short8*>(vgp + (size_t)svd * N + tn * 64 + svk);

            const short* Kb = Kb0 + (t & 1) * 2560;
            const short* Vb = Vb0 + (t & 1) * 2304;

            short8 kf[4];
#pragma unroll
            for (int c = 0; c < 4; ++c)
                kf[c] = *reinterpret_cast<const short8*>(&Kb[(c * 16 + col) * 40 + quad * 8]);

#pragma unroll
            for (int g = 0; g < 2; ++g) {
                float s[16];
#pragma unroll
                for (int c = 0; c < 4; ++c) {
                    f32x4 acc = {};
                    acc = __builtin_amdgcn_mfma_f32_16x16x32_bf16(kf[c], qf[g], acc, 0, 0, 0);
#pragma unroll
                    for (int r = 0; r < 4; ++r) s[c * 4 + r] = acc[r];
                }
                float p[16], lloc = 0.f;
#pragma unroll
                for (int i = 0; i < 16; ++i) { p[i] = exp2f(s[i]); lloc += p[i]; }
                lloc += __shfl_xor(lloc, 16, 64);
                lloc += __shfl_xor(lloc, 32, 64);
                l[g] += lloc;
#pragma unroll
                for (int c = 0; c < 4; ++c) {
                    sh4 pk;
#pragma unroll
                    for (int r = 0; r < 4; ++r) pk[r] = f2bfs(p[c * 4 + r]);
                    *reinterpret_cast<sh4*>(&P[(g * 16 + col) * 72 + c * 16 + quad * 4]) = pk;
                }
            }

#pragma unroll
            for (int kg = 0; kg < 2; ++kg) {
                short8 vf[2];
#pragma unroll
                for (int dh = 0; dh < 2; ++dh)
                    vf[dh] = *reinterpret_cast<const short8*>(&Vb[(dh * 16 + col) * 72 + kg * 32 + quad * 8]);
#pragma unroll
                for (int g = 0; g < 2; ++g) {
                    short8 pf = *reinterpret_cast<const short8*>(&P[(g * 16 + col) * 72 + kg * 32 + quad * 8]);
#pragma unroll
                    for (int dh = 0; dh < 2; ++dh)
                        oac[g][dh] = __builtin_amdgcn_mfma_f32_16x16x32_bf16(vf[dh], pf, oac[g][dh], 0, 0, 0);
                }
            }

            *reinterpret_cast<short8*>(&Kb0[((t + 1) & 1) * 2560 + skey * 40 + sd]) = kstage;
            *reinterpret_cast<short8*>(&Vb0[((t + 1) & 1) * 2304 + svd * 72 + svk]) = vstage;
            __syncthreads();
        }

        // epilogue: gated mix, pixel-major packed stores
#pragma unroll
        for (int g = 0; g < 2; ++g) {
            const int q = qbase + g * 16 + col;
            const float invl = 1.f / l[g];
            const float sqv  = sqg[b * N + q];
            const float hv   = 1.f - sqv;
            short* gp = reinterpret_cast<short*>(gt) + ((size_t)b * N + q) * C + h * HD + quad * 4;
#pragma unroll
            for (int dh = 0; dh < 2; ++dh) {
                sh4 pack;
#pragma unroll
                for (int r = 0; r < 4; ++r) {
                    int d = dh * 16 + quad * 4 + r;
                    float vb = bf2f(*reinterpret_cast<const bf16*>(vp + (size_t)d * N + q));
                    pack[r] = f2bfs(sqv * (oac[g][dh][r] * invl) + hv * vb);
                }
                *reinterpret_cast<sh4*>(gp + dh * 16) = pack;
            }
        }
    }
    grid.sync();

    // ---------------- phase 3: projection GEMM ----------------------------
    {
        short* G = reinterpret_cast<short*>(smem);   // [64][TS]

        const int mrow = (bid & 3) * 64 + wave * 16;
        const int n0   = ((bid >> 2) & 15) * 64;
        const int b    = bid >> 6;

        {
            const short* gp = reinterpret_cast<const short*>(gt) + ((size_t)b * N + n0) * C;
            const int px = tid >> 2;
            const int c0 = (tid & 3) * 64;
#pragma unroll
            for (int j = 0; j < 8; ++j) {
                short8 v = *reinterpret_cast<const short8*>(gp + (size_t)px * C + c0 + j * 8);
                *reinterpret_cast<short8*>(&G[px * TS + c0 + j * 8]) = v;
            }
        }
        __syncthreads();

        const short* Wm = reinterpret_cast<const short*>(Wb) + 3 * 65536;

        f32x4 acc[4] = {};
#pragma unroll
        for (int k0 = 0; k0 < 256; k0 += 32) {
            short8 af = *reinterpret_cast<const short8*>(Wm + (size_t)(mrow + col) * 256 + k0 + quad * 8);
#pragma unroll
            for (int cf = 0; cf < 4; ++cf) {
                short8 bfr = *reinterpret_cast<const short8*>(&G[(cf * 16 + col) * TS + k0 + quad * 8]);
                acc[cf] = __builtin_amdgcn_mfma_f32_16x16x32_bf16(af, bfr, acc[cf], 0, 0, 0);
            }
        }

        const int cr = mrow + quad * 4;
        float bias[4];
#pragma unroll
        for (int r = 0; r < 4; ++r) bias[r] = bp[cr + r];
        float* op = out + (size_t)b * C * N;
#pragma unroll
        for (int cf = 0; cf < 4; ++cf) {
            int n = n0 + cf * 16 + col;
#pragma unroll
            for (int r = 0; r < 4; ++r)
                op[(size_t)(cr + r) * N + n] = acc[cf][r] + bias[r];
        }
    }
}

// ===========================================================================
// Fallback path: the four separate kernels (baseline structure, exp2f K2),
// used only if the cooperative launch is rejected (e.g. under graph capture).
// ===========================================================================
__global__ __launch_bounds__(256) void k_prep(
    const float* __restrict__ Wq, const float* __restrict__ Wk,
    const float* __restrict__ Wv, const float* __restrict__ Wp,
    bf16* __restrict__ Wb)
{
    const int tid = threadIdx.x;
    const int mat = blockIdx.x >> 2, seg = blockIdx.x & 3;
    const float* src = (mat == 0) ? Wq : (mat == 1) ? Wk : (mat == 2) ? Wv : Wp;
    short* dst = reinterpret_cast<short*>(Wb) + (size_t)mat * 256 * 256;
#pragma unroll
    for (int i = 0; i < 16; ++i) {
        int f4 = seg * 4096 + i * 256 + tid;
        float4 v = reinterpret_cast<const float4*>(src)[f4];
        sh4 o;
        o[0] = f2bfs(v.x); o[1] = f2bfs(v.y); o[2] = f2bfs(v.z); o[3] = f2bfs(v.w);
        *reinterpret_cast<sh4*>(dst + (size_t)f4 * 4) = o;
    }
}

__global__ __launch_bounds__(256) void k_fused5(
    const float* __restrict__ x, const float* __restrict__ gq, const float* __restrict__ gk,
    const float* __restrict__ Wsq, const float* __restrict__ bsq,
    const float* __restrict__ Wsk, const float* __restrict__ bsk,
    const bf16* __restrict__ Wb,
    const float* __restrict__ bq, const float* __restrict__ bk, const float* __restrict__ bv,
    bf16* __restrict__ qo, bf16* __restrict__ ko, bf16* __restrict__ vo,
    float* __restrict__ sqg)
{
    __shared__ short T[64 * TS];
    __shared__ float sq_lds[64];
    __shared__ float sk_lds[64];

    const int tid  = threadIdx.x;
    const int wave = tid >> 6;
    const int lane = tid & 63;
    const int col  = lane & 15;
    const int quad = lane >> 4;

    const int b    = blockIdx.x >> 6;
    const int rest = blockIdx.x & 63;
    const int n0   = (rest >> 2) * 64;
    const int mq   = rest & 3;

    {
        const float* xp = x + (size_t)b * C * N + n0;
        const int row = tid >> 4;
        const int f   = tid & 15;
#pragma unroll
        for (int p = 0; p < 16; ++p) {
            int c = p * 16 + row;
            float4 v = *reinterpret_cast<const float4*>(xp + (size_t)c * N + f * 4);
            T[(f * 4 + 0) * TS + c] = f2bfs(v.x);
            T[(f * 4 + 1) * TS + c] = f2bfs(v.y);
            T[(f * 4 + 2) * TS + c] = f2bfs(v.z);
            T[(f * 4 + 3) * TS + c] = f2bfs(v.w);
        }
    }
    __syncthreads();

    if (wave == 0) {
        const float* wsrc = (col < 4) ? (Wsq + col * C) : (Wsk + (col & 3) * C);
        f32x4 ga[4] = {};
#pragma unroll
        for (int k0 = 0; k0 < 256; k0 += 32) {
            float4 w0 = *reinterpret_cast<const float4*>(wsrc + k0 + quad * 8);
            float4 w1 = *reinterpret_cast<const float4*>(wsrc + k0 + quad * 8 + 4);
            short8 af = cvt8(w0, w1);
#pragma unroll
            for (int cf = 0; cf < 4; ++cf) {
                short8 bfr = *reinterpret_cast<const short8*>(&T[(cf * 16 + col) * TS + k0 + quad * 8]);
                ga[cf] = __builtin_amdgcn_mfma_f32_16x16x32_bf16(af, bfr, ga[cf], 0, 0, 0);
            }
        }
        if (quad < 2) {
            const float* bsrc = (quad == 0) ? bsq : bsk;
            const float* gsrc = (quad == 0) ? gq : gk;
#pragma unroll
            for (int cf = 0; cf < 4; ++cf) {
                int n = n0 + cf * 16 + col;
                float a[4];
#pragma unroll
                for (int r = 0; r < 4; ++r)
                    a[r] = ga[cf][r] + bsrc[r] + gsrc[(size_t)b * 4 * N + (size_t)r * N + n];
                float mx = fmaxf(fmaxf(a[0], a[1]), fmaxf(a[2], a[3]));
                float e = 0.f;
#pragma unroll
                for (int r = 0; r < 4; ++r) e += __expf(a[r] - mx);
                float p0 = __expf(a[0] - mx) / e;
                if (quad == 0) {
                    sq_lds[cf * 16 + col] = p0;
                    if (mq == 0) sqg[b * N + n] = p0;
                } else {
                    sk_lds[cf * 16 + col] = p0;
                }
            }
        }
    }
    __syncthreads();

    const short* Ws = reinterpret_cast<const short*>(Wb);
    const int mbase = mq * 192 + wave * 48;
    f32x4 acc[3][4] = {};
#pragma unroll
    for (int k0 = 0; k0 < 256; k0 += 32) {
        short8 bfr[4];
#pragma unroll
        for (int cf = 0; cf < 4; ++cf)
            bfr[cf] = *reinterpret_cast<const short8*>(&T[(cf * 16 + col) * TS + k0 + quad * 8]);
#pragma unroll
        for (int i = 0; i < 3; ++i) {
            int m = mbase + i * 16;
            const short* wr = Ws + (size_t)(m >> 8) * 65536
                              + (size_t)((m & 255) + col) * 256 + k0 + quad * 8;
            short8 af = *reinterpret_cast<const short8*>(wr);
#pragma unroll
            for (int cf = 0; cf < 4; ++cf)
                acc[i][cf] = __builtin_amdgcn_mfma_f32_16x16x32_bf16(af, bfr[cf], acc[i][cf], 0, 0, 0);
        }
    }
#pragma unroll
    for (int i = 0; i < 3; ++i) {
        int m = mbase + i * 16;
        int mat = m >> 8;
        int cr  = (m & 255) + quad * 4;
        const float* bb = (mat == 0) ? bq : (mat == 1) ? bk : bv;
        float bias[4];
#pragma unroll
        for (int r = 0; r < 4; ++r) bias[r] = bb[cr + r];
        if (mat < 2) {
            short* op = reinterpret_cast<short*>((mat == 0) ? qo : ko) + (size_t)b * N * C;
#pragma unroll
            for (int cf = 0; cf < 4; ++cf) {
                int n = n0 + cf * 16 + col;
                float g = (mat == 0) ? sq_lds[cf * 16 + col] * SCALE_E
                                     : sk_lds[cf * 16 + col];
                sh4 pack;
#pragma unroll
                for (int r = 0; r < 4; ++r) pack[r] = f2bfs((acc[i][cf][r] + bias[r]) * g);
                *reinterpret_cast<sh4*>(op + (size_t)n * C + cr) = pack;
            }
        } else {
            bf16* op = vo + (size_t)b * C * N;
#pragma unroll
            for (int cf = 0; cf < 4; ++cf) {
                int n = n0 + cf * 16 + col;
#pragma unroll
                for (int r = 0; r < 4; ++r)
                    op[(size_t)(cr + r) * N + n] = __float2bfloat16(acc[i][cf][r] + bias[r]);
            }
        }
    }
}

__global__ __launch_bounds__(256) void k_attn6(
    const bf16* __restrict__ qo, const bf16* __restrict__ ko,
    const bf16* __restrict__ vo, const float* __restrict__ sqg,
    bf16* __restrict__ gt)
{
    __shared__ short P_lds[4][32 * 72];
    __shared__ short K_lds[2][64 * 40];
    __shared__ short V_lds[2][32 * 72];

    const int tid  = threadIdx.x;
    const int wave = tid >> 6;
    const int lane = tid & 63;
    const int col  = lane & 15;
    const int quad = lane >> 4;

    const int b = blockIdx.x >> 6;
    const int h = (blockIdx.x >> 3) & 7;
    const int qbase = (blockIdx.x & 7) * 128 + wave * 32;

    const int skey = tid >> 2;
    const int sd   = (tid & 3) * 8;
    const int svd  = tid >> 3;
    const int svk  = (tid & 7) * 8;

    const short* kgp = reinterpret_cast<const short*>(ko) + (size_t)b * N * C + h * HD;
    const short* vgp = reinterpret_cast<const short*>(vo) + (size_t)b * C * N + (size_t)h * HD * N;
    const short* vp  = vgp;

    short8 qf[2];
    {
        const short* qp = reinterpret_cast<const short*>(qo) + (size_t)b * N * C + h * HD + quad * 8;
#pragma unroll
        for (int g = 0; g < 2; ++g)
            qf[g] = *reinterpret_cast<const short8*>(qp + (size_t)(qbase + g * 16 + col) * C);
    }

    float l[2] = {};
    f32x4 oac[2][2] = {};
    short* P = P_lds[wave];

    short8 kstage = *reinterpret_cast<const short8*>(kgp + (size_t)skey * C + sd);
    short8 vstage = *reinterpret_cast<const short8*>(vgp + (size_t)svd * N + svk);
    *reinterpret_cast<short8*>(&K_lds[0][skey * 40 + sd]) = kstage;
    *reinterpret_cast<short8*>(&V_lds[0][svd * 72 + svk]) = vstage;
    __syncthreads();

    for (int t = 0; t < 16; ++t) {
        const int tn = (t + 1) & 15;
        kstage = *reinterpret_cast<const short8*>(kgp + (size_t)(tn * 64 + skey) * C + sd);
        vstage = *reinterpret_cast<const short8*>(vgp + (size_t)svd * N + tn * 64 + svk);

        const short* Kb = K_lds[t & 1];
        const short* Vb = V_lds[t & 1];

        short8 kf[4];
#pragma unroll
        for (int c = 0; c < 4; ++c)
            kf[c] = *reinterpret_cast<const short8*>(&Kb[(c * 16 + col) * 40 + quad * 8]);

#pragma unroll
        for (int g = 0; g < 2; ++g) {
            float s[16];
#pragma unroll
            for (int c = 0; c < 4; ++c) {
                f32x4 acc = {};
                acc = __builtin_amdgcn_mfma_f32_16x16x32_bf16(kf[c], qf[g], acc, 0, 0, 0);
#pragma unroll
                for (int r = 0; r < 4; ++r) s[c * 4 + r] = acc[r];
            }
            float p[16], lloc = 0.f;
#pragma unroll
            for (int i = 0; i < 16; ++i) { p[i] = exp2f(s[i]); lloc += p[i]; }
            lloc += __shfl_xor(lloc, 16, 64);
            lloc += __shfl_xor(lloc, 32, 64);
            l[g] += lloc;
#pragma unroll
            for (int c = 0; c < 4; ++c) {
                sh4 pk;
#pragma unroll
                for (int r = 0; r < 4; ++r) pk[r] = f2bfs(p[c * 4 + r]);
                *reinterpret_cast<sh4*>(&P[(g * 16 + col) * 72 + c * 16 + quad * 4]) = pk;
            }
        }

#pragma unroll
        for (int kg = 0; kg < 2; ++kg) {
            short8 vf[2];
#pragma unroll
            for (int dh = 0; dh < 2; ++dh)
                vf[dh] = *reinterpret_cast<const short8*>(&Vb[(dh * 16 + col) * 72 + kg * 32 + quad * 8]);
#pragma unroll
            for (int g = 0; g < 2; ++g) {
                short8 pf = *reinterpret_cast<const short8*>(&P[(g * 16 + col) * 72 + kg * 32 + quad * 8]);
#pragma unroll
                for (int dh = 0; dh < 2; ++dh)
                    oac[g][dh] = __builtin_amdgcn_mfma_f32_16x16x32_bf16(vf[dh], pf, oac[g][dh], 0, 0, 0);
            }
        }

        *reinterpret_cast<short8*>(&K_lds[(t + 1) & 1][skey * 40 + sd]) = kstage;
        *reinterpret_cast<short8*>(&V_lds[(t + 1) & 1][svd * 72 + svk]) = vstage;
        __syncthreads();
    }

#pragma unroll
    for (int g = 0; g < 2; ++g) {
        const int q = qbase + g * 16 + col;
        const float invl = 1.f / l[g];
        const float sqv  = sqg[b * N + q];
        const float hv   = 1.f - sqv;
        short* gp = reinterpret_cast<short*>(gt) + ((size_t)b * N + q) * C + h * HD + quad * 4;
#pragma unroll
        for (int dh = 0; dh < 2; ++dh) {
            sh4 pack;
#pragma unroll
            for (int r = 0; r < 4; ++r) {
                int d = dh * 16 + quad * 4 + r;
                float vb = bf2f(*reinterpret_cast<const bf16*>(vp + (size_t)d * N + q));
                pack[r] = f2bfs(sqv * (oac[g][dh][r] * invl) + hv * vb);
            }
            *reinterpret_cast<sh4*>(gp + dh * 16) = pack;
        }
    }
}

__global__ __launch_bounds__(256) void k_projm5(
    const bf16* __restrict__ gt, const bf16* __restrict__ Wpb,
    const float* __restrict__ bp, float* __restrict__ out)
{
    __shared__ short G[64 * TS];

    const int tid  = threadIdx.x;
    const int wave = tid >> 6, lane = tid & 63;
    const int col  = lane & 15, quad = lane >> 4;
    const int mrow = blockIdx.x * 64 + wave * 16;
    const int b    = blockIdx.z;
    const int n0   = blockIdx.y * 64;

    {
        const short* gp = reinterpret_cast<const short*>(gt) + ((size_t)b * N + n0) * C;
        const int px = tid >> 2;
        const int c0 = (tid & 3) * 64;
#pragma unroll
        for (int j = 0; j < 8; ++j) {
            short8 v = *reinterpret_cast<const short8*>(gp + (size_t)px * C + c0 + j * 8);
            *reinterpret_cast<short8*>(&G[px * TS + c0 + j * 8]) = v;
        }
    }
    __syncthreads();

    const short* Wm = reinterpret_cast<const short*>(Wpb);

    f32x4 acc[4] = {};
#pragma unroll
    for (int k0 = 0; k0 < 256; k0 += 32) {
        short8 af = *reinterpret_cast<const short8*>(Wm + (size_t)(mrow + col) * 256 + k0 + quad * 8);
#pragma unroll
        for (int cf = 0; cf < 4; ++cf) {
            short8 bfr = *reinterpret_cast<const short8*>(&G[(cf * 16 + col) * TS + k0 + quad * 8]);
            acc[cf] = __builtin_amdgcn_mfma_f32_16x16x32_bf16(af, bfr, acc[cf], 0, 0, 0);
        }
    }

    const int cr = mrow + quad * 4;
    float bias[4];
#pragma unroll
    for (int r = 0; r < 4; ++r) bias[r] = bp[cr + r];
    float* op = out + (size_t)b * C * N;
#pragma unroll
    for (int cf = 0; cf < 4; ++cf) {
        int n = n0 + cf * 16 + col;
#pragma unroll
        for (int r = 0; r < 4; ++r)
            op[(size_t)(cr + r) * N + n] = acc[cf][r] + bias[r];
    }
}

// ---------------------------------------------------------------------------
// Workspace (bytes):
//   [0, 32K)        sqg f32 [8][1024]
//   [32K, 544K)     Wb bf16 [4][256][256]  (q,k,v,p)
//   [544K, +4M)     qo bf16 [8][1024][256] (pixel-major, sq*SCALE*log2e folded)
//   +4M             ko bf16 [8][1024][256] (pixel-major, sk folded)
//   +4M             vo bf16 [8][256][1024] (d-major)
//   +4M             gt bf16 [8][1024][256] (gated rows, pixel-major)
// ---------------------------------------------------------------------------
extern "C" void kernel_launch(void* const* d_in, const int* in_sizes, int n_in,
                              void* d_out, int out_size, void* d_ws, size_t ws_size,
                              hipStream_t stream)
{
    const float* x   = (const float*)d_in[0];
    const float* gq  = (const float*)d_in[1];
    const float* gk  = (const float*)d_in[2];
    const float* Wsq = (const float*)d_in[3];
    const float* bsq = (const float*)d_in[4];
    const float* Wsk = (const float*)d_in[5];
    const float* bsk = (const float*)d_in[6];
    const float* Wq  = (const float*)d_in[7];
    const float* bq  = (const float*)d_in[8];
    const float* Wk  = (const float*)d_in[9];
    const float* bk  = (const float*)d_in[10];
    const float* Wv  = (const float*)d_in[11];
    const float* bv  = (const float*)d_in[12];
    const float* Wp  = (const float*)d_in[13];
    const float* bp  = (const float*)d_in[14];

    char* ws = (char*)d_ws;
    float* sqg = (float*)ws;
    bf16* Wb   = (bf16*)(ws + 32768);
    bf16* qo   = (bf16*)(ws + 32768 + 524288);
    bf16* ko   = qo + (size_t)Bn * N * C;
    bf16* vo   = ko + (size_t)Bn * N * C;
    bf16* gt   = vo + (size_t)Bn * C * N;
    float* out = (float*)d_out;

    void* args[] = { (void*)&x, (void*)&gq, (void*)&gk, (void*)&Wsq, (void*)&bsq,
                     (void*)&Wsk, (void*)&bsk, (void*)&Wq, (void*)&bq, (void*)&Wk,
                     (void*)&bk, (void*)&Wv, (void*)&bv, (void*)&Wp, (void*)&bp,
                     (void*)&Wb, (void*)&qo, (void*)&ko, (void*)&vo, (void*)&gt,
                     (void*)&sqg, (void*)&out };
    hipError_t err = hipLaunchCooperativeKernel(reinterpret_cast<const void*>(k_all),
                                                dim3(512), dim3(256), args, 0, stream);
    if (err != hipSuccess) {
        // fallback: original 4-kernel pipeline
        k_prep<<<16, 256, 0, stream>>>(Wq, Wk, Wv, Wp, Wb);
        k_fused5<<<512, 256, 0, stream>>>(x, gq, gk, Wsq, bsq, Wsk, bsk,
                                          Wb, bq, bk, bv, qo, ko, vo, sqg);
        k_attn6<<<512, 256, 0, stream>>>(qo, ko, vo, sqg, gt);
        k_projm5<<<dim3(4, 16, 8), 256, 0, stream>>>(gt, Wb + 3 * 65536, bp, out);
    }
}

// Round 4
// 195.768 us; speedup vs baseline: 1.6430x; 1.6430x over previous
//
#include <hip/hip_runtime.h>
#include <hip/hip_bf16.h>
#include <math.h>

typedef __hip_bfloat16 bf16;
typedef __attribute__((ext_vector_type(8))) short short8;
typedef __attribute__((ext_vector_type(4))) short sh4;
typedef __attribute__((ext_vector_type(4))) float f32x4;

static __device__ __forceinline__ float bf2f(bf16 h) { return __bfloat162float(h); }
static __device__ __forceinline__ short f2bfs(float f) {
    bf16 h = __float2bfloat16(f);
    return *reinterpret_cast<short*>(&h);
}
static __device__ __forceinline__ short8 cvt8(float4 a, float4 b) {
    short8 o;
    o[0] = f2bfs(a.x); o[1] = f2bfs(a.y); o[2] = f2bfs(a.z); o[3] = f2bfs(a.w);
    o[4] = f2bfs(b.x); o[5] = f2bfs(b.y); o[6] = f2bfs(b.z); o[7] = f2bfs(b.w);
    return o;
}

constexpr int Bn = 8;
constexpr int C  = 256;
constexpr int N  = 1024;     // H*W
constexpr int NH = 8;
constexpr int HD = 32;
constexpr int TS = 264;      // LDS tile stride (shorts)
constexpr float SCALE = 0.17677669529663687f;  // 1/sqrt(32)
// log2(e) folded into the q scale so K2's softmax can use exp2f (v_exp_f32 is 2^x)
constexpr float SCALE_E = 0.17677669529663687f * 1.4426950408889634f;

// DIAGNOSTIC: repeat each kernel body REP times so our dispatches exceed the
// harness's ~45 us fill dispatches and appear in rocprof top-5 with counters.
// Bodies are pure functions of their inputs -> bit-identical outputs.
// Remove (REP=1) next round once per-kernel attribution is known.
constexpr int REP = 2;

// T-tile XOR swizzle (shorts): element (px, c) lives at  px*TS + (c ^ SW(px)).
// SW flips short-bits 3..5 -> 16B chunks permute within the row; b128 reads of
// 8 consecutive c (chunk-aligned) stay contiguous + 16B aligned.
static __device__ __forceinline__ int tsw(int px) { return ((px >> 2) & 7) << 3; }

// ---------------------------------------------------------------------------
// K0: convert Wq|Wk|Wv|Wp f32 -> Wb bf16 [4][256][256]. 256 blocks (was 16).
// ---------------------------------------------------------------------------
__global__ __launch_bounds__(256) void k_prep(
    const float* __restrict__ Wq, const float* __restrict__ Wk,
    const float* __restrict__ Wv, const float* __restrict__ Wp,
    bf16* __restrict__ Wb)
{
    const int idx = blockIdx.x * 256 + threadIdx.x;     // 65536 float4s total
    const int mat = idx >> 14;
    const float* src = (mat == 0) ? Wq : (mat == 1) ? Wk : (mat == 2) ? Wv : Wp;
    float4 v = reinterpret_cast<const float4*>(src)[idx & 16383];
    sh4 o;
    o[0] = f2bfs(v.x); o[1] = f2bfs(v.y); o[2] = f2bfs(v.z); o[3] = f2bfs(v.w);
    reinterpret_cast<sh4*>(reinterpret_cast<short*>(Wb))[idx] = o;
}

// ---------------------------------------------------------------------------
// K1: fused transpose + gates + q/k/v GEMM.
// This round: T-store XOR swizzle (16-way -> ~4-way bank conflict) and
// head-major qo/ko [b][h][n][32] so K2 reads dense lines.
// ---------------------------------------------------------------------------
__global__ __launch_bounds__(256) void k_fused5(
    const float* __restrict__ x, const float* __restrict__ gq, const float* __restrict__ gk,
    const float* __restrict__ Wsq, const float* __restrict__ bsq,
    const float* __restrict__ Wsk, const float* __restrict__ bsk,
    const bf16* __restrict__ Wb,
    const float* __restrict__ bq, const float* __restrict__ bk, const float* __restrict__ bv,
    bf16* __restrict__ qo, bf16* __restrict__ ko, bf16* __restrict__ vo,
    float* __restrict__ sqg)
{
    __shared__ short T[64 * TS];     // [pixel][c swizzled], 33.8 KB
    __shared__ float sq_lds[64];
    __shared__ float sk_lds[64];

    const int tid  = threadIdx.x;
    const int wave = tid >> 6;
    const int lane = tid & 63;
    const int col  = lane & 15;
    const int quad = lane >> 4;

    const int b    = blockIdx.x >> 6;
    const int rest = blockIdx.x & 63;
    const int n0   = (rest >> 2) * 64;   // 16 tiles of 64 px
    const int mq   = rest & 3;           // m-quarter (192 rows)

    for (int rep = 0; rep < REP; ++rep) {

    // ---- stage x^T tile: 256 c-rows x 64 pixels (swizzled stores) ----
    {
        const float* xp = x + (size_t)b * C * N + n0;
        const int row = tid >> 4;        // 0..15 (c within pass)
        const int f   = tid & 15;        // float4 within 64 pixels
        const int sw  = (f & 7) << 3;    // tsw(4f+r) == (f&7)<<3 for r<4
#pragma unroll
        for (int p = 0; p < 16; ++p) {
            int c = p * 16 + row;
            float4 v = *reinterpret_cast<const float4*>(xp + (size_t)c * N + f * 4);
            int cs = c ^ sw;
            T[(f * 4 + 0) * TS + cs] = f2bfs(v.x);
            T[(f * 4 + 1) * TS + cs] = f2bfs(v.y);
            T[(f * 4 + 2) * TS + cs] = f2bfs(v.z);
            T[(f * 4 + 3) * TS + cs] = f2bfs(v.w);
        }
    }
    __syncthreads();

    // ---- gates (wave 0 only): logits via MFMA over 4 B-frags ----
    if (wave == 0) {
        const float* wsrc = (col < 4) ? (Wsq + col * C) : (Wsk + (col & 3) * C);
        f32x4 ga[4] = {};
#pragma unroll
        for (int k0 = 0; k0 < 256; k0 += 32) {
            float4 w0 = *reinterpret_cast<const float4*>(wsrc + k0 + quad * 8);
            float4 w1 = *reinterpret_cast<const float4*>(wsrc + k0 + quad * 8 + 4);
            short8 af = cvt8(w0, w1);
#pragma unroll
            for (int cf = 0; cf < 4; ++cf) {
                int px = cf * 16 + col;
                short8 bfr = *reinterpret_cast<const short8*>(
                    &T[px * TS + ((k0 + quad * 8) ^ tsw(px))]);
                ga[cf] = __builtin_amdgcn_mfma_f32_16x16x32_bf16(af, bfr, ga[cf], 0, 0, 0);
            }
        }
        if (quad < 2) {
            const float* bsrc = (quad == 0) ? bsq : bsk;
            const float* gsrc = (quad == 0) ? gq : gk;
#pragma unroll
            for (int cf = 0; cf < 4; ++cf) {
                int n = n0 + cf * 16 + col;
                float a[4];
#pragma unroll
                for (int r = 0; r < 4; ++r)
                    a[r] = ga[cf][r] + bsrc[r] + gsrc[(size_t)b * 4 * N + (size_t)r * N + n];
                float mx = fmaxf(fmaxf(a[0], a[1]), fmaxf(a[2], a[3]));
                float e = 0.f;
#pragma unroll
                for (int r = 0; r < 4; ++r) e += __expf(a[r] - mx);
                float p0 = __expf(a[0] - mx) / e;
                if (quad == 0) {
                    sq_lds[cf * 16 + col] = p0;
                    if (mq == 0) sqg[b * N + n] = p0;
                } else {
                    sk_lds[cf * 16 + col] = p0;
                }
            }
        }
    }
    __syncthreads();

    // ---- GEMM: this block's 192-row M quarter; 3 A-frags x 4 B-frags ----
    const short* Ws = reinterpret_cast<const short*>(Wb);
    const int mbase = mq * 192 + wave * 48;
    f32x4 acc[3][4] = {};
#pragma unroll
    for (int k0 = 0; k0 < 256; k0 += 32) {
        short8 bfr[4];
#pragma unroll
        for (int cf = 0; cf < 4; ++cf) {
            int px = cf * 16 + col;
            bfr[cf] = *reinterpret_cast<const short8*>(
                &T[px * TS + ((k0 + quad * 8) ^ tsw(px))]);
        }
#pragma unroll
        for (int i = 0; i < 3; ++i) {
            int m = mbase + i * 16;
            const short* wr = Ws + (size_t)(m >> 8) * 65536
                              + (size_t)((m & 255) + col) * 256 + k0 + quad * 8;
            short8 af = *reinterpret_cast<const short8*>(wr);
#pragma unroll
            for (int cf = 0; cf < 4; ++cf)
                acc[i][cf] = __builtin_amdgcn_mfma_f32_16x16x32_bf16(af, bfr[cf], acc[i][cf], 0, 0, 0);
        }
    }
    // epilogue (per-frag mat handles quarters spanning matrix boundaries)
#pragma unroll
    for (int i = 0; i < 3; ++i) {
        int m = mbase + i * 16;
        int mat = m >> 8;
        int cr  = (m & 255) + quad * 4;
        const float* bb = (mat == 0) ? bq : (mat == 1) ? bk : bv;
        float bias[4];
#pragma unroll
        for (int r = 0; r < 4; ++r) bias[r] = bb[cr + r];
        if (mat < 2) {
            // head-major [b][h][n][32]
            const int hh = cr >> 5, dd = cr & 31;
            short* op = reinterpret_cast<short*>((mat == 0) ? qo : ko)
                        + ((size_t)b * NH + hh) * N * HD + dd;
#pragma unroll
            for (int cf = 0; cf < 4; ++cf) {
                int n = n0 + cf * 16 + col;
                float g = (mat == 0) ? sq_lds[cf * 16 + col] * SCALE_E
                                     : sk_lds[cf * 16 + col];
                sh4 pack;
#pragma unroll
                for (int r = 0; r < 4; ++r) pack[r] = f2bfs((acc[i][cf][r] + bias[r]) * g);
                *reinterpret_cast<sh4*>(op + (size_t)n * HD) = pack;
            }
        } else {
            bf16* op = vo + (size_t)b * C * N;
#pragma unroll
            for (int cf = 0; cf < 4; ++cf) {
                int n = n0 + cf * 16 + col;
#pragma unroll
                for (int r = 0; r < 4; ++r)
                    op[(size_t)(cr + r) * N + n] = __float2bfloat16(acc[i][cf][r] + bias[r]);
            }
        }
    }
    __syncthreads();
    } // rep
}

// ---------------------------------------------------------------------------
// K2: attention + gated mix, double-buffered K/V LDS staging (128-q tile,
// baseline-proven structure). Head-major qo/ko reads; exp2f softmax.
// ---------------------------------------------------------------------------
__global__ __launch_bounds__(256) void k_attn6(
    const bf16* __restrict__ qo, const bf16* __restrict__ ko,
    const bf16* __restrict__ vo, const float* __restrict__ sqg,
    bf16* __restrict__ gt)
{
    __shared__ short P_lds[4][32 * 72];   // 36.9 KB
    __shared__ short K_lds[2][64 * 40];   // 10.2 KB
    __shared__ short V_lds[2][32 * 72];   //  9.2 KB  (total 56.3 KB)

    const int tid  = threadIdx.x;
    const int wave = tid >> 6;
    const int lane = tid & 63;
    const int col  = lane & 15;
    const int quad = lane >> 4;

    const int b = blockIdx.x >> 6;
    const int h = (blockIdx.x >> 3) & 7;
    const int qbase = (blockIdx.x & 7) * 128 + wave * 32;

    const int skey = tid >> 2;          // 0..63
    const int sd   = (tid & 3) * 8;     // 0,8,16,24
    const int svd  = tid >> 3;          // 0..31
    const int svk  = (tid & 7) * 8;     // 0..56

    // head-major K/Q: [b][h][n][32]
    const short* kgp = reinterpret_cast<const short*>(ko) + ((size_t)b * NH + h) * N * HD;
    const short* qp0 = reinterpret_cast<const short*>(qo) + ((size_t)b * NH + h) * N * HD;
    const short* vgp = reinterpret_cast<const short*>(vo) + (size_t)b * C * N + (size_t)h * HD * N;
    const short* vp  = vgp;

    for (int rep = 0; rep < REP; ++rep) {

    short8 qf[2];
#pragma unroll
    for (int g = 0; g < 2; ++g)
        qf[g] = *reinterpret_cast<const short8*>(
            qp0 + (size_t)(qbase + g * 16 + col) * HD + quad * 8);

    float l[2] = {};
    f32x4 oac[2][2] = {};   // [g][dh]
    short* P = P_lds[wave];

    short8 kstage = *reinterpret_cast<const short8*>(kgp + (size_t)skey * HD + sd);
    short8 vstage = *reinterpret_cast<const short8*>(vgp + (size_t)svd * N + svk);
    *reinterpret_cast<short8*>(&K_lds[0][skey * 40 + sd]) = kstage;
    *reinterpret_cast<short8*>(&V_lds[0][svd * 72 + svk]) = vstage;
    __syncthreads();

    for (int t = 0; t < 16; ++t) {
        const int tn = (t + 1) & 15;
        kstage = *reinterpret_cast<const short8*>(kgp + (size_t)(tn * 64 + skey) * HD + sd);
        vstage = *reinterpret_cast<const short8*>(vgp + (size_t)svd * N + tn * 64 + svk);

        const short* Kb = K_lds[t & 1];
        const short* Vb = V_lds[t & 1];

        short8 kf[4];
#pragma unroll
        for (int c = 0; c < 4; ++c)
            kf[c] = *reinterpret_cast<const short8*>(&Kb[(c * 16 + col) * 40 + quad * 8]);

#pragma unroll
        for (int g = 0; g < 2; ++g) {
            float s[16];
#pragma unroll
            for (int c = 0; c < 4; ++c) {
                f32x4 acc = {};
                acc = __builtin_amdgcn_mfma_f32_16x16x32_bf16(kf[c], qf[g], acc, 0, 0, 0);
#pragma unroll
                for (int r = 0; r < 4; ++r) s[c * 4 + r] = acc[r];
            }
            float p[16], lloc = 0.f;
#pragma unroll
            for (int i = 0; i < 16; ++i) { p[i] = exp2f(s[i]); lloc += p[i]; }
            lloc += __shfl_xor(lloc, 16, 64);
            lloc += __shfl_xor(lloc, 32, 64);
            l[g] += lloc;
#pragma unroll
            for (int c = 0; c < 4; ++c) {
                sh4 pk;
#pragma unroll
                for (int r = 0; r < 4; ++r) pk[r] = f2bfs(p[c * 4 + r]);
                *reinterpret_cast<sh4*>(&P[(g * 16 + col) * 72 + c * 16 + quad * 4]) = pk;
            }
        }

#pragma unroll
        for (int kg = 0; kg < 2; ++kg) {
            short8 vf[2];
#pragma unroll
            for (int dh = 0; dh < 2; ++dh)
                vf[dh] = *reinterpret_cast<const short8*>(&Vb[(dh * 16 + col) * 72 + kg * 32 + quad * 8]);
#pragma unroll
            for (int g = 0; g < 2; ++g) {
                short8 pf = *reinterpret_cast<const short8*>(&P[(g * 16 + col) * 72 + kg * 32 + quad * 8]);
#pragma unroll
                for (int dh = 0; dh < 2; ++dh)
                    oac[g][dh] = __builtin_amdgcn_mfma_f32_16x16x32_bf16(vf[dh], pf, oac[g][dh], 0, 0, 0);
            }
        }

        *reinterpret_cast<short8*>(&K_lds[(t + 1) & 1][skey * 40 + sd]) = kstage;
        *reinterpret_cast<short8*>(&V_lds[(t + 1) & 1][svd * 72 + svk]) = vstage;
        __syncthreads();
    }

    // epilogue: gated mix, pixel-major packed stores
#pragma unroll
    for (int g = 0; g < 2; ++g) {
        const int q = qbase + g * 16 + col;
        const float invl = 1.f / l[g];
        const float sqv  = sqg[b * N + q];
        const float hv   = 1.f - sqv;
        short* gp = reinterpret_cast<short*>(gt) + ((size_t)b * N + q) * C + h * HD + quad * 4;
#pragma unroll
        for (int dh = 0; dh < 2; ++dh) {
            sh4 pack;
#pragma unroll
            for (int r = 0; r < 4; ++r) {
                int d = dh * 16 + quad * 4 + r;
                float vb = bf2f(*reinterpret_cast<const bf16*>(vp + (size_t)d * N + q));
                pack[r] = f2bfs(sqv * (oac[g][dh][r] * invl) + hv * vb);
            }
            *reinterpret_cast<sh4*>(gp + dh * 16) = pack;
        }
    }
    __syncthreads();
    } // rep
}

// ---------------------------------------------------------------------------
// K3: projection MFMA GEMM, 64m x 64n blocks with staged G tile.
// ---------------------------------------------------------------------------
__global__ __launch_bounds__(256) void k_projm5(
    const bf16* __restrict__ gt, const bf16* __restrict__ Wpb,
    const float* __restrict__ bp, float* __restrict__ out)
{
    __shared__ short G[64 * TS];   // [pixel][c], 33.8 KB

    const int tid  = threadIdx.x;
    const int wave = tid >> 6, lane = tid & 63;
    const int col  = lane & 15, quad = lane >> 4;
    const int mrow = blockIdx.x * 64 + wave * 16;    // wave owns 16 m rows
    const int b    = blockIdx.z;
    const int n0   = blockIdx.y * 64;

    for (int rep = 0; rep < REP; ++rep) {

    // ---- stage gt tile: 64 pixels x 256 c (no transpose, no convert) ----
    {
        const short* gp = reinterpret_cast<const short*>(gt) + ((size_t)b * N + n0) * C;
        const int px = tid >> 2;          // 0..63
        const int c0 = (tid & 3) * 64;    // 0,64,128,192
#pragma unroll
        for (int j = 0; j < 8; ++j) {
            short8 v = *reinterpret_cast<const short8*>(gp + (size_t)px * C + c0 + j * 8);
            *reinterpret_cast<short8*>(&G[px * TS + c0 + j * 8]) = v;
        }
    }
    __syncthreads();

    const short* Wm = reinterpret_cast<const short*>(Wpb);

    f32x4 acc[4] = {};   // [nfrag]
#pragma unroll
    for (int k0 = 0; k0 < 256; k0 += 32) {
        short8 af = *reinterpret_cast<const short8*>(Wm + (size_t)(mrow + col) * 256 + k0 + quad * 8);
#pragma unroll
        for (int cf = 0; cf < 4; ++cf) {
            short8 bfr = *reinterpret_cast<const short8*>(&G[(cf * 16 + col) * TS + k0 + quad * 8]);
            acc[cf] = __builtin_amdgcn_mfma_f32_16x16x32_bf16(af, bfr, acc[cf], 0, 0, 0);
        }
    }

    const int cr = mrow + quad * 4;
    float bias[4];
#pragma unroll
    for (int r = 0; r < 4; ++r) bias[r] = bp[cr + r];
    float* op = out + (size_t)b * C * N;
#pragma unroll
    for (int cf = 0; cf < 4; ++cf) {
        int n = n0 + cf * 16 + col;
#pragma unroll
        for (int r = 0; r < 4; ++r)
            op[(size_t)(cr + r) * N + n] = acc[cf][r] + bias[r];
    }
    __syncthreads();
    } // rep
}

// ---------------------------------------------------------------------------
// Workspace (bytes):
//   [0, 32K)        sqg f32 [8][1024]
//   [32K, 544K)     Wb bf16 [4][256][256]  (q,k,v,p)
//   [544K, +4M)     qo bf16 [8][8][1024][32] (HEAD-major, sq*SCALE*log2e folded)
//   +4M             ko bf16 [8][8][1024][32] (HEAD-major, sk folded)
//   +4M             vo bf16 [8][256][1024] (d-major)
//   +4M             gt bf16 [8][1024][256] (gated rows, pixel-major)
// ---------------------------------------------------------------------------
extern "C" void kernel_launch(void* const* d_in, const int* in_sizes, int n_in,
                              void* d_out, int out_size, void* d_ws, size_t ws_size,
                              hipStream_t stream)
{
    const float* x   = (const float*)d_in[0];
    const float* gq  = (const float*)d_in[1];
    const float* gk  = (const float*)d_in[2];
    const float* Wsq = (const float*)d_in[3];
    const float* bsq = (const float*)d_in[4];
    const float* Wsk = (const float*)d_in[5];
    const float* bsk = (const float*)d_in[6];
    const float* Wq  = (const float*)d_in[7];
    const float* bq  = (const float*)d_in[8];
    const float* Wk  = (const float*)d_in[9];
    const float* bk  = (const float*)d_in[10];
    const float* Wv  = (const float*)d_in[11];
    const float* bv  = (const float*)d_in[12];
    const float* Wp  = (const float*)d_in[13];
    const float* bp  = (const float*)d_in[14];

    char* ws = (char*)d_ws;
    float* sqg = (float*)ws;
    bf16* Wb   = (bf16*)(ws + 32768);
    bf16* qo   = (bf16*)(ws + 32768 + 524288);
    bf16* ko   = qo + (size_t)Bn * N * C;
    bf16* vo   = ko + (size_t)Bn * N * C;
    bf16* gt   = vo + (size_t)Bn * C * N;
    float* out = (float*)d_out;

    k_prep<<<256, 256, 0, stream>>>(Wq, Wk, Wv, Wp, Wb);
    k_fused5<<<512, 256, 0, stream>>>(x, gq, gk, Wsq, bsq, Wsk, bsk,
                                      Wb, bq, bk, bv, qo, ko, vo, sqg);
    k_attn6<<<512, 256, 0, stream>>>(qo, ko, vo, sqg, gt);
    k_projm5<<<dim3(4, 16, 8), 256, 0, stream>>>(gt, Wb + 3 * 65536, bp, out);
}

// Round 5
// 159.545 us; speedup vs baseline: 2.0160x; 1.2270x over previous
//
#include <hip/hip_runtime.h>
#include <hip/hip_bf16.h>
#include <math.h>

typedef __hip_bfloat16 bf16;
typedef __attribute__((ext_vector_type(8))) short short8;
typedef __attribute__((ext_vector_type(4))) short sh4;
typedef __attribute__((ext_vector_type(4))) float f32x4;

static __device__ __forceinline__ float bf2f(bf16 h) { return __bfloat162float(h); }
static __device__ __forceinline__ short f2bfs(float f) {
    bf16 h = __float2bfloat16(f);
    return *reinterpret_cast<short*>(&h);
}
static __device__ __forceinline__ float bfs2f(short s) {
    unsigned u = (unsigned)(unsigned short)s << 16;
    return __builtin_bit_cast(float, u);
}
static __device__ __forceinline__ short8 cvt8(float4 a, float4 b) {
    short8 o;
    o[0] = f2bfs(a.x); o[1] = f2bfs(a.y); o[2] = f2bfs(a.z); o[3] = f2bfs(a.w);
    o[4] = f2bfs(b.x); o[5] = f2bfs(b.y); o[6] = f2bfs(b.z); o[7] = f2bfs(b.w);
    return o;
}

constexpr int Bn = 8;
constexpr int C  = 256;
constexpr int N  = 1024;     // H*W
constexpr int NH = 8;
constexpr int HD = 32;
constexpr int TS = 264;      // LDS tile stride (shorts)
// log2(e) folded into the q scale so K2's softmax can use exp2f (v_exp_f32 is 2^x)
constexpr float SCALE_E = 0.17677669529663687f * 1.4426950408889634f;

// T-tile XOR swizzle (shorts): element (px, c) lives at  px*TS + (c ^ tsw(px)).
static __device__ __forceinline__ int tsw(int px) { return ((px >> 2) & 7) << 3; }

// ---------------------------------------------------------------------------
// K0: convert Wq|Wk|Wv|Wp f32 -> Wb bf16 [4][256][256]. 256 blocks.
// ---------------------------------------------------------------------------
__global__ __launch_bounds__(256) void k_prep(
    const float* __restrict__ Wq, const float* __restrict__ Wk,
    const float* __restrict__ Wv, const float* __restrict__ Wp,
    bf16* __restrict__ Wb)
{
    const int idx = blockIdx.x * 256 + threadIdx.x;     // 65536 float4s total
    const int mat = idx >> 14;
    const float* src = (mat == 0) ? Wq : (mat == 1) ? Wk : (mat == 2) ? Wv : Wp;
    float4 v = reinterpret_cast<const float4*>(src)[idx & 16383];
    sh4 o;
    o[0] = f2bfs(v.x); o[1] = f2bfs(v.y); o[2] = f2bfs(v.z); o[3] = f2bfs(v.w);
    reinterpret_cast<sh4*>(reinterpret_cast<short*>(Wb))[idx] = o;
}

// ---------------------------------------------------------------------------
// K1: fused transpose + gates + q/k/v GEMM. 512 blocks = (b, 16 n-tile, mq).
// XOR-swizzled T stores; head-major qo/ko [b][h][n][32]; NEW: px-major vo2
// [b][n][256] written alongside d-major vo (feeds K3's fused merge).
// ---------------------------------------------------------------------------
__global__ __launch_bounds__(256) void k_fused5(
    const float* __restrict__ x, const float* __restrict__ gq, const float* __restrict__ gk,
    const float* __restrict__ Wsq, const float* __restrict__ bsq,
    const float* __restrict__ Wsk, const float* __restrict__ bsk,
    const bf16* __restrict__ Wb,
    const float* __restrict__ bq, const float* __restrict__ bk, const float* __restrict__ bv,
    bf16* __restrict__ qo, bf16* __restrict__ ko, bf16* __restrict__ vo,
    bf16* __restrict__ vo2, float* __restrict__ sqg)
{
    __shared__ short T[64 * TS];     // [pixel][c swizzled], 33.8 KB
    __shared__ float sq_lds[64];
    __shared__ float sk_lds[64];

    const int tid  = threadIdx.x;
    const int wave = tid >> 6;
    const int lane = tid & 63;
    const int col  = lane & 15;
    const int quad = lane >> 4;

    const int b    = blockIdx.x >> 6;
    const int rest = blockIdx.x & 63;
    const int n0   = (rest >> 2) * 64;   // 16 tiles of 64 px
    const int mq   = rest & 3;           // m-quarter (192 rows)

    // ---- stage x^T tile: 256 c-rows x 64 pixels (swizzled stores) ----
    {
        const float* xp = x + (size_t)b * C * N + n0;
        const int row = tid >> 4;        // 0..15 (c within pass)
        const int f   = tid & 15;        // float4 within 64 pixels
        const int sw  = (f & 7) << 3;    // tsw(4f+r) == (f&7)<<3 for r<4
#pragma unroll
        for (int p = 0; p < 16; ++p) {
            int c = p * 16 + row;
            float4 v = *reinterpret_cast<const float4*>(xp + (size_t)c * N + f * 4);
            int cs = c ^ sw;
            T[(f * 4 + 0) * TS + cs] = f2bfs(v.x);
            T[(f * 4 + 1) * TS + cs] = f2bfs(v.y);
            T[(f * 4 + 2) * TS + cs] = f2bfs(v.z);
            T[(f * 4 + 3) * TS + cs] = f2bfs(v.w);
        }
    }
    __syncthreads();

    // ---- gates (wave 0 only): logits via MFMA over 4 B-frags ----
    if (wave == 0) {
        const float* wsrc = (col < 4) ? (Wsq + col * C) : (Wsk + (col & 3) * C);
        f32x4 ga[4] = {};
#pragma unroll
        for (int k0 = 0; k0 < 256; k0 += 32) {
            float4 w0 = *reinterpret_cast<const float4*>(wsrc + k0 + quad * 8);
            float4 w1 = *reinterpret_cast<const float4*>(wsrc + k0 + quad * 8 + 4);
            short8 af = cvt8(w0, w1);
#pragma unroll
            for (int cf = 0; cf < 4; ++cf) {
                int px = cf * 16 + col;
                short8 bfr = *reinterpret_cast<const short8*>(
                    &T[px * TS + ((k0 + quad * 8) ^ tsw(px))]);
                ga[cf] = __builtin_amdgcn_mfma_f32_16x16x32_bf16(af, bfr, ga[cf], 0, 0, 0);
            }
        }
        if (quad < 2) {
            const float* bsrc = (quad == 0) ? bsq : bsk;
            const float* gsrc = (quad == 0) ? gq : gk;
#pragma unroll
            for (int cf = 0; cf < 4; ++cf) {
                int n = n0 + cf * 16 + col;
                float a[4];
#pragma unroll
                for (int r = 0; r < 4; ++r)
                    a[r] = ga[cf][r] + bsrc[r] + gsrc[(size_t)b * 4 * N + (size_t)r * N + n];
                float mx = fmaxf(fmaxf(a[0], a[1]), fmaxf(a[2], a[3]));
                float e = 0.f;
#pragma unroll
                for (int r = 0; r < 4; ++r) e += __expf(a[r] - mx);
                float p0 = __expf(a[0] - mx) / e;
                if (quad == 0) {
                    sq_lds[cf * 16 + col] = p0;
                    if (mq == 0) sqg[b * N + n] = p0;
                } else {
                    sk_lds[cf * 16 + col] = p0;
                }
            }
        }
    }
    __syncthreads();

    // ---- GEMM: this block's 192-row M quarter; 3 A-frags x 4 B-frags ----
    const short* Ws = reinterpret_cast<const short*>(Wb);
    const int mbase = mq * 192 + wave * 48;
    f32x4 acc[3][4] = {};
#pragma unroll
    for (int k0 = 0; k0 < 256; k0 += 32) {
        short8 bfr[4];
#pragma unroll
        for (int cf = 0; cf < 4; ++cf) {
            int px = cf * 16 + col;
            bfr[cf] = *reinterpret_cast<const short8*>(
                &T[px * TS + ((k0 + quad * 8) ^ tsw(px))]);
        }
#pragma unroll
        for (int i = 0; i < 3; ++i) {
            int m = mbase + i * 16;
            const short* wr = Ws + (size_t)(m >> 8) * 65536
                              + (size_t)((m & 255) + col) * 256 + k0 + quad * 8;
            short8 af = *reinterpret_cast<const short8*>(wr);
#pragma unroll
            for (int cf = 0; cf < 4; ++cf)
                acc[i][cf] = __builtin_amdgcn_mfma_f32_16x16x32_bf16(af, bfr[cf], acc[i][cf], 0, 0, 0);
        }
    }
    // epilogue (per-frag mat handles quarters spanning matrix boundaries)
#pragma unroll
    for (int i = 0; i < 3; ++i) {
        int m = mbase + i * 16;
        int mat = m >> 8;
        int cr  = (m & 255) + quad * 4;
        const float* bb = (mat == 0) ? bq : (mat == 1) ? bk : bv;
        float bias[4];
#pragma unroll
        for (int r = 0; r < 4; ++r) bias[r] = bb[cr + r];
        if (mat < 2) {
            // head-major [b][h][n][32]
            const int hh = cr >> 5, dd = cr & 31;
            short* op = reinterpret_cast<short*>((mat == 0) ? qo : ko)
                        + ((size_t)b * NH + hh) * N * HD + dd;
#pragma unroll
            for (int cf = 0; cf < 4; ++cf) {
                int n = n0 + cf * 16 + col;
                float g = (mat == 0) ? sq_lds[cf * 16 + col] * SCALE_E
                                     : sk_lds[cf * 16 + col];
                sh4 pack;
#pragma unroll
                for (int r = 0; r < 4; ++r) pack[r] = f2bfs((acc[i][cf][r] + bias[r]) * g);
                *reinterpret_cast<sh4*>(op + (size_t)n * HD) = pack;
            }
        } else {
            bf16* op  = vo + (size_t)b * C * N;
            short* o2 = reinterpret_cast<short*>(vo2) + (size_t)b * N * C + cr;
#pragma unroll
            for (int cf = 0; cf < 4; ++cf) {
                int n = n0 + cf * 16 + col;
                sh4 pack;
#pragma unroll
                for (int r = 0; r < 4; ++r) {
                    float v = acc[i][cf][r] + bias[r];
                    pack[r] = f2bfs(v);
                    op[(size_t)(cr + r) * N + n] = __float2bfloat16(v);
                }
                *reinterpret_cast<sh4*>(o2 + (size_t)n * C) = pack;
            }
        }
    }
}

// ---------------------------------------------------------------------------
// K2: attention, kv-split 2-way. 1024 blocks = (b, h, 8 q-tile, 2 kv-half)
// = 4 blocks/CU (LDS 37.9 KB). Each block processes 8 kv-tiles and writes
// UNNORMALIZED f32 O-partials + l-partials (no max in softmax -> partials
// are directly additive; merge happens in K3's staging).
// ---------------------------------------------------------------------------
__global__ __launch_bounds__(256, 4) void k_attn7(
    const bf16* __restrict__ qo, const bf16* __restrict__ ko,
    const bf16* __restrict__ vo, float* __restrict__ Op, float* __restrict__ lp)
{
    __shared__ short P_lds[4][32 * 72];   // 18.4 KB
    __shared__ short K_lds[2][64 * 40];   // 10.2 KB
    __shared__ short V_lds[2][32 * 72];   //  9.2 KB  (total 37.9 KB)

    const int tid  = threadIdx.x;
    const int wave = tid >> 6;
    const int lane = tid & 63;
    const int col  = lane & 15;
    const int quad = lane >> 4;

    const int bid = blockIdx.x;
    const int b  = bid >> 7;
    const int h  = (bid >> 4) & 7;
    const int qt = (bid >> 1) & 7;
    const int s  = bid & 1;
    const int qbase = qt * 128 + wave * 32;
    const int t0 = s * 8;                 // this block's kv half: tiles t0..t0+7

    const int skey = tid >> 2;          // 0..63
    const int sd   = (tid & 3) * 8;     // 0,8,16,24
    const int svd  = tid >> 3;          // 0..31
    const int svk  = (tid & 7) * 8;     // 0..56

    const short* kgp = reinterpret_cast<const short*>(ko) + ((size_t)b * NH + h) * N * HD;
    const short* qp0 = reinterpret_cast<const short*>(qo) + ((size_t)b * NH + h) * N * HD;
    const short* vgp = reinterpret_cast<const short*>(vo) + (size_t)b * C * N + (size_t)h * HD * N;

    short8 qf[2];
#pragma unroll
    for (int g = 0; g < 2; ++g)
        qf[g] = *reinterpret_cast<const short8*>(
            qp0 + (size_t)(qbase + g * 16 + col) * HD + quad * 8);

    float l[2] = {};
    f32x4 oac[2][2] = {};   // [g][dh]
    short* P = P_lds[wave];

    short8 kstage = *reinterpret_cast<const short8*>(kgp + (size_t)(t0 * 64 + skey) * HD + sd);
    short8 vstage = *reinterpret_cast<const short8*>(vgp + (size_t)svd * N + t0 * 64 + svk);
    *reinterpret_cast<short8*>(&K_lds[0][skey * 40 + sd]) = kstage;
    *reinterpret_cast<short8*>(&V_lds[0][svd * 72 + svk]) = vstage;
    __syncthreads();

    for (int t = 0; t < 8; ++t) {
        const int tn = t0 + ((t + 1) & 7);
        kstage = *reinterpret_cast<const short8*>(kgp + (size_t)(tn * 64 + skey) * HD + sd);
        vstage = *reinterpret_cast<const short8*>(vgp + (size_t)svd * N + tn * 64 + svk);

        const short* Kb = K_lds[t & 1];
        const short* Vb = V_lds[t & 1];

        short8 kf[4];
#pragma unroll
        for (int c = 0; c < 4; ++c)
            kf[c] = *reinterpret_cast<const short8*>(&Kb[(c * 16 + col) * 40 + quad * 8]);

#pragma unroll
        for (int g = 0; g < 2; ++g) {
            float sc[16];
#pragma unroll
            for (int c = 0; c < 4; ++c) {
                f32x4 acc = {};
                acc = __builtin_amdgcn_mfma_f32_16x16x32_bf16(kf[c], qf[g], acc, 0, 0, 0);
#pragma unroll
                for (int r = 0; r < 4; ++r) sc[c * 4 + r] = acc[r];
            }
            float p[16], lloc = 0.f;
#pragma unroll
            for (int i = 0; i < 16; ++i) { p[i] = exp2f(sc[i]); lloc += p[i]; }
            lloc += __shfl_xor(lloc, 16, 64);
            lloc += __shfl_xor(lloc, 32, 64);
            l[g] += lloc;
#pragma unroll
            for (int c = 0; c < 4; ++c) {
                sh4 pk;
#pragma unroll
                for (int r = 0; r < 4; ++r) pk[r] = f2bfs(p[c * 4 + r]);
                *reinterpret_cast<sh4*>(&P[(g * 16 + col) * 72 + c * 16 + quad * 4]) = pk;
            }
        }

#pragma unroll
        for (int kg = 0; kg < 2; ++kg) {
            short8 vf[2];
#pragma unroll
            for (int dh = 0; dh < 2; ++dh)
                vf[dh] = *reinterpret_cast<const short8*>(&Vb[(dh * 16 + col) * 72 + kg * 32 + quad * 8]);
#pragma unroll
            for (int g = 0; g < 2; ++g) {
                short8 pf = *reinterpret_cast<const short8*>(&P[(g * 16 + col) * 72 + kg * 32 + quad * 8]);
#pragma unroll
                for (int dh = 0; dh < 2; ++dh)
                    oac[g][dh] = __builtin_amdgcn_mfma_f32_16x16x32_bf16(vf[dh], pf, oac[g][dh], 0, 0, 0);
            }
        }

        *reinterpret_cast<short8*>(&K_lds[(t + 1) & 1][skey * 40 + sd]) = kstage;
        *reinterpret_cast<short8*>(&V_lds[(t + 1) & 1][svd * 72 + svk]) = vstage;
        __syncthreads();
    }

    // epilogue: write unnormalized partials (f32) + row-sums
    float* Ob = Op + (size_t)s * Bn * N * C;
#pragma unroll
    for (int g = 0; g < 2; ++g) {
        const int q = qbase + g * 16 + col;
        float* orow = Ob + ((size_t)b * N + q) * C + h * HD;
#pragma unroll
        for (int dh = 0; dh < 2; ++dh)
            *reinterpret_cast<f32x4*>(orow + dh * 16 + quad * 4) = oac[g][dh];
        if (quad == 0)
            lp[((size_t)(s * Bn + b) * NH + h) * N + q] = l[g];
    }
}

// ---------------------------------------------------------------------------
// K3: merge partials + gated mix + projection GEMM. 1024 blocks =
// (4 m, 32 n-tiles of 32px, 8 b) = 4/CU. Staging computes
// gt = sqv*(O0+O1)/(l0+l1) + (1-sqv)*v on the fly (gt buffer eliminated).
// ---------------------------------------------------------------------------
__global__ __launch_bounds__(256, 4) void k_projm6(
    const bf16* __restrict__ Wpb, const float* __restrict__ bp,
    const float* __restrict__ Op, const float* __restrict__ lp,
    const bf16* __restrict__ vo2, const float* __restrict__ sqg,
    float* __restrict__ out)
{
    __shared__ short G[32 * TS];   // 16.9 KB

    const int tid  = threadIdx.x;
    const int wave = tid >> 6, lane = tid & 63;
    const int col  = lane & 15, quad = lane >> 4;
    const int mrow = blockIdx.x * 64 + wave * 16;    // wave owns 16 m rows
    const int n0   = blockIdx.y * 32;
    const int b    = blockIdx.z;

    // ---- merge + stage: 32 px x 256 c ----
    {
        const int px = tid >> 3;          // 0..31
        const int c0 = (tid & 7) * 32;    // one 32-ch head group per thread
        const int q  = n0 + px;
        const int hh = c0 >> 5;
        const float* o0 = Op + ((size_t)b * N + q) * C;
        const float* o1 = o0 + (size_t)Bn * N * C;
        const short* v2 = reinterpret_cast<const short*>(vo2) + ((size_t)b * N + q) * C;
        const float sqv = sqg[b * N + q];
        const float hv  = 1.f - sqv;
        const float il  = 1.f / (lp[((size_t)b * NH + hh) * N + q]
                               + lp[((size_t)(Bn + b) * NH + hh) * N + q]);
        const float w   = sqv * il;
#pragma unroll
        for (int j = 0; j < 4; ++j) {
            int c = c0 + j * 8;
            float4 a0 = *reinterpret_cast<const float4*>(o0 + c);
            float4 a1 = *reinterpret_cast<const float4*>(o0 + c + 4);
            float4 b0 = *reinterpret_cast<const float4*>(o1 + c);
            float4 b1 = *reinterpret_cast<const float4*>(o1 + c + 4);
            short8 vv = *reinterpret_cast<const short8*>(v2 + c);
            short8 pk;
            pk[0] = f2bfs(w * (a0.x + b0.x) + hv * bfs2f(vv[0]));
            pk[1] = f2bfs(w * (a0.y + b0.y) + hv * bfs2f(vv[1]));
            pk[2] = f2bfs(w * (a0.z + b0.z) + hv * bfs2f(vv[2]));
            pk[3] = f2bfs(w * (a0.w + b0.w) + hv * bfs2f(vv[3]));
            pk[4] = f2bfs(w * (a1.x + b1.x) + hv * bfs2f(vv[4]));
            pk[5] = f2bfs(w * (a1.y + b1.y) + hv * bfs2f(vv[5]));
            pk[6] = f2bfs(w * (a1.z + b1.z) + hv * bfs2f(vv[6]));
            pk[7] = f2bfs(w * (a1.w + b1.w) + hv * bfs2f(vv[7]));
            *reinterpret_cast<short8*>(&G[px * TS + c]) = pk;
        }
    }
    __syncthreads();

    const short* Wm = reinterpret_cast<const short*>(Wpb);

    f32x4 acc[2] = {};   // [nfrag]
#pragma unroll
    for (int k0 = 0; k0 < 256; k0 += 32) {
        short8 af = *reinterpret_cast<const short8*>(Wm + (size_t)(mrow + col) * 256 + k0 + quad * 8);
#pragma unroll
        for (int cf = 0; cf < 2; ++cf) {
            short8 bfr = *reinterpret_cast<const short8*>(&G[(cf * 16 + col) * TS + k0 + quad * 8]);
            acc[cf] = __builtin_amdgcn_mfma_f32_16x16x32_bf16(af, bfr, acc[cf], 0, 0, 0);
        }
    }

    const int cr = mrow + quad * 4;
    float bias[4];
#pragma unroll
    for (int r = 0; r < 4; ++r) bias[r] = bp[cr + r];
    float* op = out + (size_t)b * C * N;
#pragma unroll
    for (int cf = 0; cf < 2; ++cf) {
        int n = n0 + cf * 16 + col;
#pragma unroll
        for (int r = 0; r < 4; ++r)
            op[(size_t)(cr + r) * N + n] = acc[cf][r] + bias[r];
    }
}

// ---------------------------------------------------------------------------
// Workspace (bytes):
//   [0, 32K)      sqg f32 [8][1024]
//   [32K, 544K)   Wb bf16 [4][256][256]
//   +4M           qo bf16 [8][8][1024][32]  (head-major, sq*SCALE*log2e folded)
//   +4M           ko bf16 [8][8][1024][32]  (head-major, sk folded)
//   +4M           vo bf16 [8][256][1024]    (d-major, K2 V staging)
//   +4M           vo2 bf16 [8][1024][256]   (px-major, K3 merge)
//   +16.8M        Op f32 [2][8][1024][256]  (kv-half partial O, unnormalized)
//   +512K         lp f32 [2][8][8][1024]    (kv-half partial row-sums)
//   total ~34.6 MB
// ---------------------------------------------------------------------------
extern "C" void kernel_launch(void* const* d_in, const int* in_sizes, int n_in,
                              void* d_out, int out_size, void* d_ws, size_t ws_size,
                              hipStream_t stream)
{
    const float* x   = (const float*)d_in[0];
    const float* gq  = (const float*)d_in[1];
    const float* gk  = (const float*)d_in[2];
    const float* Wsq = (const float*)d_in[3];
    const float* bsq = (const float*)d_in[4];
    const float* Wsk = (const float*)d_in[5];
    const float* bsk = (const float*)d_in[6];
    const float* Wq  = (const float*)d_in[7];
    const float* bq  = (const float*)d_in[8];
    const float* Wk  = (const float*)d_in[9];
    const float* bk  = (const float*)d_in[10];
    const float* Wv  = (const float*)d_in[11];
    const float* bv  = (const float*)d_in[12];
    const float* Wp  = (const float*)d_in[13];
    const float* bp  = (const float*)d_in[14];

    char* ws = (char*)d_ws;
    float* sqg = (float*)ws;
    bf16* Wb   = (bf16*)(ws + 32768);
    bf16* qo   = (bf16*)(ws + 32768 + 524288);
    bf16* ko   = qo + (size_t)Bn * N * C;
    bf16* vo   = ko + (size_t)Bn * N * C;
    bf16* vo2  = vo + (size_t)Bn * N * C;
    float* Op  = (float*)(vo2 + (size_t)Bn * N * C);
    float* lp  = Op + (size_t)2 * Bn * N * C;
    float* out = (float*)d_out;

    k_prep<<<256, 256, 0, stream>>>(Wq, Wk, Wv, Wp, Wb);
    k_fused5<<<512, 256, 0, stream>>>(x, gq, gk, Wsq, bsq, Wsk, bsk,
                                      Wb, bq, bk, bv, qo, ko, vo, vo2, sqg);
    k_attn7<<<1024, 256, 0, stream>>>(qo, ko, vo, Op, lp);
    k_projm6<<<dim3(4, 32, 8), 256, 0, stream>>>(Wb + 3 * 65536, bp, Op, lp,
                                                 vo2, sqg, out);
}

// Round 6
// 146.394 us; speedup vs baseline: 2.1972x; 1.0898x over previous
//
#include <hip/hip_runtime.h>
#include <hip/hip_bf16.h>
#include <math.h>

typedef __hip_bfloat16 bf16;
typedef __attribute__((ext_vector_type(8))) short short8;
typedef __attribute__((ext_vector_type(4))) short sh4;
typedef __attribute__((ext_vector_type(4))) float f32x4;

static __device__ __forceinline__ float bf2f(bf16 h) { return __bfloat162float(h); }
static __device__ __forceinline__ short f2bfs(float f) {
    bf16 h = __float2bfloat16(f);
    return *reinterpret_cast<short*>(&h);
}
static __device__ __forceinline__ short8 cvt8(float4 a, float4 b) {
    short8 o;
    o[0] = f2bfs(a.x); o[1] = f2bfs(a.y); o[2] = f2bfs(a.z); o[3] = f2bfs(a.w);
    o[4] = f2bfs(b.x); o[5] = f2bfs(b.y); o[6] = f2bfs(b.z); o[7] = f2bfs(b.w);
    return o;
}

constexpr int Bn = 8;
constexpr int C  = 256;
constexpr int N  = 1024;     // H*W
constexpr int NH = 8;
constexpr int HD = 32;
constexpr int TS = 264;      // LDS tile stride (shorts)
// log2(e) folded into the q scale so K2's softmax can use exp2f (v_exp_f32 is 2^x)
constexpr float SCALE_E = 0.17677669529663687f * 1.4426950408889634f;

// T-tile XOR swizzle (shorts): element (px, c) lives at  px*TS + (c ^ tsw(px)).
static __device__ __forceinline__ int tsw(int px) { return ((px >> 2) & 7) << 3; }

// ---------------------------------------------------------------------------
// K1: fused transpose + gates + q/k/v GEMM. 512 blocks = (b, 16 n-tile, mq).
// Weight A-frags converted f32->bf16 INLINE (k_prep eliminated).
// XOR-swizzled T stores; head-major qo/ko [b][h][n][32].
// ---------------------------------------------------------------------------
__global__ __launch_bounds__(256) void k_fused6(
    const float* __restrict__ x, const float* __restrict__ gq, const float* __restrict__ gk,
    const float* __restrict__ Wsq, const float* __restrict__ bsq,
    const float* __restrict__ Wsk, const float* __restrict__ bsk,
    const float* __restrict__ Wq, const float* __restrict__ bq,
    const float* __restrict__ Wk, const float* __restrict__ bk,
    const float* __restrict__ Wv, const float* __restrict__ bv,
    bf16* __restrict__ qo, bf16* __restrict__ ko, bf16* __restrict__ vo,
    float* __restrict__ sqg)
{
    __shared__ short T[64 * TS];     // [pixel][c swizzled], 33.8 KB
    __shared__ float sq_lds[64];
    __shared__ float sk_lds[64];

    const int tid  = threadIdx.x;
    const int wave = tid >> 6;
    const int lane = tid & 63;
    const int col  = lane & 15;
    const int quad = lane >> 4;

    const int b    = blockIdx.x >> 6;
    const int rest = blockIdx.x & 63;
    const int n0   = (rest >> 2) * 64;   // 16 tiles of 64 px
    const int mq   = rest & 3;           // m-quarter (192 rows)

    // ---- stage x^T tile: 256 c-rows x 64 pixels (swizzled stores) ----
    {
        const float* xp = x + (size_t)b * C * N + n0;
        const int row = tid >> 4;        // 0..15 (c within pass)
        const int f   = tid & 15;        // float4 within 64 pixels
        const int sw  = (f & 7) << 3;    // tsw(4f+r) == (f&7)<<3 for r<4
#pragma unroll
        for (int p = 0; p < 16; ++p) {
            int c = p * 16 + row;
            float4 v = *reinterpret_cast<const float4*>(xp + (size_t)c * N + f * 4);
            int cs = c ^ sw;
            T[(f * 4 + 0) * TS + cs] = f2bfs(v.x);
            T[(f * 4 + 1) * TS + cs] = f2bfs(v.y);
            T[(f * 4 + 2) * TS + cs] = f2bfs(v.z);
            T[(f * 4 + 3) * TS + cs] = f2bfs(v.w);
        }
    }
    __syncthreads();

    // ---- gates (wave 0 only): logits via MFMA over 4 B-frags ----
    if (wave == 0) {
        const float* wsrc = (col < 4) ? (Wsq + col * C) : (Wsk + (col & 3) * C);
        f32x4 ga[4] = {};
#pragma unroll
        for (int k0 = 0; k0 < 256; k0 += 32) {
            float4 w0 = *reinterpret_cast<const float4*>(wsrc + k0 + quad * 8);
            float4 w1 = *reinterpret_cast<const float4*>(wsrc + k0 + quad * 8 + 4);
            short8 af = cvt8(w0, w1);
#pragma unroll
            for (int cf = 0; cf < 4; ++cf) {
                int px = cf * 16 + col;
                short8 bfr = *reinterpret_cast<const short8*>(
                    &T[px * TS + ((k0 + quad * 8) ^ tsw(px))]);
                ga[cf] = __builtin_amdgcn_mfma_f32_16x16x32_bf16(af, bfr, ga[cf], 0, 0, 0);
            }
        }
        if (quad < 2) {
            const float* bsrc = (quad == 0) ? bsq : bsk;
            const float* gsrc = (quad == 0) ? gq : gk;
#pragma unroll
            for (int cf = 0; cf < 4; ++cf) {
                int n = n0 + cf * 16 + col;
                float a[4];
#pragma unroll
                for (int r = 0; r < 4; ++r)
                    a[r] = ga[cf][r] + bsrc[r] + gsrc[(size_t)b * 4 * N + (size_t)r * N + n];
                float mx = fmaxf(fmaxf(a[0], a[1]), fmaxf(a[2], a[3]));
                float e = 0.f;
#pragma unroll
                for (int r = 0; r < 4; ++r) e += __expf(a[r] - mx);
                float p0 = __expf(a[0] - mx) / e;
                if (quad == 0) {
                    sq_lds[cf * 16 + col] = p0;
                    if (mq == 0) sqg[b * N + n] = p0;
                } else {
                    sk_lds[cf * 16 + col] = p0;
                }
            }
        }
    }
    __syncthreads();

    // ---- GEMM: this block's 192-row M quarter; 3 A-frags x 4 B-frags ----
    // A-frags: load f32 weight rows directly, cvt inline (no Wb buffer).
    const int mbase = mq * 192 + wave * 48;
    const float* wrow[3];
#pragma unroll
    for (int i = 0; i < 3; ++i) {
        int m = mbase + i * 16;
        int mat = m >> 8;
        const float* Wsel = (mat == 0) ? Wq : (mat == 1) ? Wk : Wv;
        wrow[i] = Wsel + (size_t)((m & 255) + col) * 256;
    }
    f32x4 acc[3][4] = {};
#pragma unroll
    for (int k0 = 0; k0 < 256; k0 += 32) {
        short8 bfr[4];
#pragma unroll
        for (int cf = 0; cf < 4; ++cf) {
            int px = cf * 16 + col;
            bfr[cf] = *reinterpret_cast<const short8*>(
                &T[px * TS + ((k0 + quad * 8) ^ tsw(px))]);
        }
#pragma unroll
        for (int i = 0; i < 3; ++i) {
            float4 w0 = *reinterpret_cast<const float4*>(wrow[i] + k0 + quad * 8);
            float4 w1 = *reinterpret_cast<const float4*>(wrow[i] + k0 + quad * 8 + 4);
            short8 af = cvt8(w0, w1);
#pragma unroll
            for (int cf = 0; cf < 4; ++cf)
                acc[i][cf] = __builtin_amdgcn_mfma_f32_16x16x32_bf16(af, bfr[cf], acc[i][cf], 0, 0, 0);
        }
    }
    // epilogue (per-frag mat handles quarters spanning matrix boundaries)
#pragma unroll
    for (int i = 0; i < 3; ++i) {
        int m = mbase + i * 16;
        int mat = m >> 8;
        int cr  = (m & 255) + quad * 4;
        const float* bb = (mat == 0) ? bq : (mat == 1) ? bk : bv;
        float bias[4];
#pragma unroll
        for (int r = 0; r < 4; ++r) bias[r] = bb[cr + r];
        if (mat < 2) {
            // head-major [b][h][n][32]
            const int hh = cr >> 5, dd = cr & 31;
            short* op = reinterpret_cast<short*>((mat == 0) ? qo : ko)
                        + ((size_t)b * NH + hh) * N * HD + dd;
#pragma unroll
            for (int cf = 0; cf < 4; ++cf) {
                int n = n0 + cf * 16 + col;
                float g = (mat == 0) ? sq_lds[cf * 16 + col] * SCALE_E
                                     : sk_lds[cf * 16 + col];
                sh4 pack;
#pragma unroll
                for (int r = 0; r < 4; ++r) pack[r] = f2bfs((acc[i][cf][r] + bias[r]) * g);
                *reinterpret_cast<sh4*>(op + (size_t)n * HD) = pack;
            }
        } else {
            bf16* op = vo + (size_t)b * C * N;
#pragma unroll
            for (int cf = 0; cf < 4; ++cf) {
                int n = n0 + cf * 16 + col;
#pragma unroll
                for (int r = 0; r < 4; ++r)
                    op[(size_t)(cr + r) * N + n] = __float2bfloat16(acc[i][cf][r] + bias[r]);
            }
        }
    }
}

// ---------------------------------------------------------------------------
// K2: attention + gated mix, double-buffered K/V LDS staging (128-q tile,
// proven structure; 31 us/pass measured at REP=2). Head-major qo/ko reads;
// exp2f softmax. NEW: bijective XCD swizzle so the 8 q-tile blocks of one
// (b,h) share an XCD -> 128 KB K/V panel is L2-resident.
// ---------------------------------------------------------------------------
__global__ __launch_bounds__(256) void k_attn6(
    const bf16* __restrict__ qo, const bf16* __restrict__ ko,
    const bf16* __restrict__ vo, const float* __restrict__ sqg,
    bf16* __restrict__ gt)
{
    __shared__ short P_lds[4][32 * 72];   // 18.4 KB
    __shared__ short K_lds[2][64 * 40];   // 10.2 KB
    __shared__ short V_lds[2][32 * 72];   //  9.2 KB  (total 37.9 KB)

    const int tid  = threadIdx.x;
    const int wave = tid >> 6;
    const int lane = tid & 63;
    const int col  = lane & 15;
    const int quad = lane >> 4;

    // XCD swizzle: dispatch round-robins bid over 8 XCDs. xcd = bid&7 gets
    // chunks [xcd*8, xcd*8+8) -> all 8 q-tiles of a (b,h) on one XCD.
    const int bid   = blockIdx.x;
    const int xcd   = bid & 7;
    const int idx   = bid >> 3;            // 0..63
    const int chunk = xcd * 8 + (idx >> 3);  // (b,h) 0..63
    const int qt    = idx & 7;
    const int b = chunk >> 3;
    const int h = chunk & 7;
    const int qbase = qt * 128 + wave * 32;

    const int skey = tid >> 2;          // 0..63
    const int sd   = (tid & 3) * 8;     // 0,8,16,24
    const int svd  = tid >> 3;          // 0..31
    const int svk  = (tid & 7) * 8;     // 0..56

    // head-major K/Q: [b][h][n][32]
    const short* kgp = reinterpret_cast<const short*>(ko) + ((size_t)b * NH + h) * N * HD;
    const short* qp0 = reinterpret_cast<const short*>(qo) + ((size_t)b * NH + h) * N * HD;
    const short* vgp = reinterpret_cast<const short*>(vo) + (size_t)b * C * N + (size_t)h * HD * N;
    const short* vp  = vgp;

    short8 qf[2];
#pragma unroll
    for (int g = 0; g < 2; ++g)
        qf[g] = *reinterpret_cast<const short8*>(
            qp0 + (size_t)(qbase + g * 16 + col) * HD + quad * 8);

    float l[2] = {};
    f32x4 oac[2][2] = {};   // [g][dh]
    short* P = P_lds[wave];

    short8 kstage = *reinterpret_cast<const short8*>(kgp + (size_t)skey * HD + sd);
    short8 vstage = *reinterpret_cast<const short8*>(vgp + (size_t)svd * N + svk);
    *reinterpret_cast<short8*>(&K_lds[0][skey * 40 + sd]) = kstage;
    *reinterpret_cast<short8*>(&V_lds[0][svd * 72 + svk]) = vstage;
    __syncthreads();

    for (int t = 0; t < 16; ++t) {
        const int tn = (t + 1) & 15;
        kstage = *reinterpret_cast<const short8*>(kgp + (size_t)(tn * 64 + skey) * HD + sd);
        vstage = *reinterpret_cast<const short8*>(vgp + (size_t)svd * N + tn * 64 + svk);

        const short* Kb = K_lds[t & 1];
        const short* Vb = V_lds[t & 1];

        short8 kf[4];
#pragma unroll
        for (int c = 0; c < 4; ++c)
            kf[c] = *reinterpret_cast<const short8*>(&Kb[(c * 16 + col) * 40 + quad * 8]);

#pragma unroll
        for (int g = 0; g < 2; ++g) {
            float s[16];
#pragma unroll
            for (int c = 0; c < 4; ++c) {
                f32x4 acc = {};
                acc = __builtin_amdgcn_mfma_f32_16x16x32_bf16(kf[c], qf[g], acc, 0, 0, 0);
#pragma unroll
                for (int r = 0; r < 4; ++r) s[c * 4 + r] = acc[r];
            }
            float p[16], lloc = 0.f;
#pragma unroll
            for (int i = 0; i < 16; ++i) { p[i] = exp2f(s[i]); lloc += p[i]; }
            lloc += __shfl_xor(lloc, 16, 64);
            lloc += __shfl_xor(lloc, 32, 64);
            l[g] += lloc;
#pragma unroll
            for (int c = 0; c < 4; ++c) {
                sh4 pk;
#pragma unroll
                for (int r = 0; r < 4; ++r) pk[r] = f2bfs(p[c * 4 + r]);
                *reinterpret_cast<sh4*>(&P[(g * 16 + col) * 72 + c * 16 + quad * 4]) = pk;
            }
        }

#pragma unroll
        for (int kg = 0; kg < 2; ++kg) {
            short8 vf[2];
#pragma unroll
            for (int dh = 0; dh < 2; ++dh)
                vf[dh] = *reinterpret_cast<const short8*>(&Vb[(dh * 16 + col) * 72 + kg * 32 + quad * 8]);
#pragma unroll
            for (int g = 0; g < 2; ++g) {
                short8 pf = *reinterpret_cast<const short8*>(&P[(g * 16 + col) * 72 + kg * 32 + quad * 8]);
#pragma unroll
                for (int dh = 0; dh < 2; ++dh)
                    oac[g][dh] = __builtin_amdgcn_mfma_f32_16x16x32_bf16(vf[dh], pf, oac[g][dh], 0, 0, 0);
            }
        }

        *reinterpret_cast<short8*>(&K_lds[(t + 1) & 1][skey * 40 + sd]) = kstage;
        *reinterpret_cast<short8*>(&V_lds[(t + 1) & 1][svd * 72 + svk]) = vstage;
        __syncthreads();
    }

    // epilogue: gated mix, pixel-major packed stores
#pragma unroll
    for (int g = 0; g < 2; ++g) {
        const int q = qbase + g * 16 + col;
        const float invl = 1.f / l[g];
        const float sqv  = sqg[b * N + q];
        const float hv   = 1.f - sqv;
        short* gp = reinterpret_cast<short*>(gt) + ((size_t)b * N + q) * C + h * HD + quad * 4;
#pragma unroll
        for (int dh = 0; dh < 2; ++dh) {
            sh4 pack;
#pragma unroll
            for (int r = 0; r < 4; ++r) {
                int d = dh * 16 + quad * 4 + r;
                float vb = bf2f(*reinterpret_cast<const bf16*>(vp + (size_t)d * N + q));
                pack[r] = f2bfs(sqv * (oac[g][dh][r] * invl) + hv * vb);
            }
            *reinterpret_cast<sh4*>(gp + dh * 16) = pack;
        }
    }
}

// ---------------------------------------------------------------------------
// K3: projection MFMA GEMM, 64m x 64n blocks with staged G tile.
// Wp A-frags converted f32->bf16 inline (no Wb).
// ---------------------------------------------------------------------------
__global__ __launch_bounds__(256) void k_projm7(
    const bf16* __restrict__ gt, const float* __restrict__ Wp,
    const float* __restrict__ bp, float* __restrict__ out)
{
    __shared__ short G[64 * TS];   // [pixel][c], 33.8 KB

    const int tid  = threadIdx.x;
    const int wave = tid >> 6, lane = tid & 63;
    const int col  = lane & 15, quad = lane >> 4;
    const int mrow = blockIdx.x * 64 + wave * 16;    // wave owns 16 m rows
    const int b    = blockIdx.z;
    const int n0   = blockIdx.y * 64;

    // ---- stage gt tile: 64 pixels x 256 c (no transpose, no convert) ----
    {
        const short* gp = reinterpret_cast<const short*>(gt) + ((size_t)b * N + n0) * C;
        const int px = tid >> 2;          // 0..63
        const int c0 = (tid & 3) * 64;    // 0,64,128,192
#pragma unroll
        for (int j = 0; j < 8; ++j) {
            short8 v = *reinterpret_cast<const short8*>(gp + (size_t)px * C + c0 + j * 8);
            *reinterpret_cast<short8*>(&G[px * TS + c0 + j * 8]) = v;
        }
    }
    __syncthreads();

    const float* wrow = Wp + (size_t)(mrow + col) * 256;

    f32x4 acc[4] = {};   // [nfrag]
#pragma unroll
    for (int k0 = 0; k0 < 256; k0 += 32) {
        float4 w0 = *reinterpret_cast<const float4*>(wrow + k0 + quad * 8);
        float4 w1 = *reinterpret_cast<const float4*>(wrow + k0 + quad * 8 + 4);
        short8 af = cvt8(w0, w1);
#pragma unroll
        for (int cf = 0; cf < 4; ++cf) {
            short8 bfr = *reinterpret_cast<const short8*>(&G[(cf * 16 + col) * TS + k0 + quad * 8]);
            acc[cf] = __builtin_amdgcn_mfma_f32_16x16x32_bf16(af, bfr, acc[cf], 0, 0, 0);
        }
    }

    const int cr = mrow + quad * 4;
    float bias[4];
#pragma unroll
    for (int r = 0; r < 4; ++r) bias[r] = bp[cr + r];
    float* op = out + (size_t)b * C * N;
#pragma unroll
    for (int cf = 0; cf < 4; ++cf) {
        int n = n0 + cf * 16 + col;
#pragma unroll
        for (int r = 0; r < 4; ++r)
            op[(size_t)(cr + r) * N + n] = acc[cf][r] + bias[r];
    }
}

// ---------------------------------------------------------------------------
// Workspace (bytes):
//   [0, 32K)      sqg f32 [8][1024]
//   [32K, +4M)    qo bf16 [8][8][1024][32]  (head-major, sq*SCALE*log2e folded)
//   +4M           ko bf16 [8][8][1024][32]  (head-major, sk folded)
//   +4M           vo bf16 [8][256][1024]    (d-major)
//   +4M           gt bf16 [8][1024][256]    (gated rows, pixel-major)
// ---------------------------------------------------------------------------
extern "C" void kernel_launch(void* const* d_in, const int* in_sizes, int n_in,
                              void* d_out, int out_size, void* d_ws, size_t ws_size,
                              hipStream_t stream)
{
    const float* x   = (const float*)d_in[0];
    const float* gq  = (const float*)d_in[1];
    const float* gk  = (const float*)d_in[2];
    const float* Wsq = (const float*)d_in[3];
    const float* bsq = (const float*)d_in[4];
    const float* Wsk = (const float*)d_in[5];
    const float* bsk = (const float*)d_in[6];
    const float* Wq  = (const float*)d_in[7];
    const float* bq  = (const float*)d_in[8];
    const float* Wk  = (const float*)d_in[9];
    const float* bk  = (const float*)d_in[10];
    const float* Wv  = (const float*)d_in[11];
    const float* bv  = (const float*)d_in[12];
    const float* Wp  = (const float*)d_in[13];
    const float* bp  = (const float*)d_in[14];

    char* ws = (char*)d_ws;
    float* sqg = (float*)ws;
    bf16* qo   = (bf16*)(ws + 32768);
    bf16* ko   = qo + (size_t)Bn * N * C;
    bf16* vo   = ko + (size_t)Bn * N * C;
    bf16* gt   = vo + (size_t)Bn * C * N;
    float* out = (float*)d_out;

    k_fused6<<<512, 256, 0, stream>>>(x, gq, gk, Wsq, bsq, Wsk, bsk,
                                      Wq, bq, Wk, bk, Wv, bv, qo, ko, vo, sqg);
    k_attn6<<<512, 256, 0, stream>>>(qo, ko, vo, sqg, gt);
    k_projm7<<<dim3(4, 16, 8), 256, 0, stream>>>(gt, Wp, bp, out);
}

// Round 7
// 139.886 us; speedup vs baseline: 2.2994x; 1.0465x over previous
//
#include <hip/hip_runtime.h>
#include <hip/hip_bf16.h>
#include <math.h>

typedef __hip_bfloat16 bf16;
typedef __attribute__((ext_vector_type(8))) short short8;
typedef __attribute__((ext_vector_type(4))) short sh4;
typedef __attribute__((ext_vector_type(4))) float f32x4;

static __device__ __forceinline__ float bf2f(bf16 h) { return __bfloat162float(h); }
static __device__ __forceinline__ short f2bfs(float f) {
    bf16 h = __float2bfloat16(f);
    return *reinterpret_cast<short*>(&h);
}
static __device__ __forceinline__ short8 cvt8(float4 a, float4 b) {
    short8 o;
    o[0] = f2bfs(a.x); o[1] = f2bfs(a.y); o[2] = f2bfs(a.z); o[3] = f2bfs(a.w);
    o[4] = f2bfs(b.x); o[5] = f2bfs(b.y); o[6] = f2bfs(b.z); o[7] = f2bfs(b.w);
    return o;
}

constexpr int Bn = 8;
constexpr int C  = 256;
constexpr int N  = 1024;     // H*W
constexpr int NH = 8;
constexpr int HD = 32;
constexpr int TS = 264;      // LDS tile stride (shorts)
// log2(e) folded into the q scale so K2's softmax can use exp2f (v_exp_f32 is 2^x)
constexpr float SCALE_E = 0.17677669529663687f * 1.4426950408889634f;

// T-tile XOR swizzle (shorts): element (px, c) lives at  px*TS + (c ^ tsw(px)).
static __device__ __forceinline__ int tsw(int px) { return ((px >> 2) & 7) << 3; }

// ---------------------------------------------------------------------------
// K0: convert Wq|Wk|Wv|Wp f32 -> Wb bf16 [4][256][256]. 256 blocks.
// (Keeping the separate prep dispatch: R6 proved inline cvt in the GEMM
// inner loop is a VALU bomb; bf16 weights from L2 are the right tradeoff.)
// ---------------------------------------------------------------------------
__global__ __launch_bounds__(256) void k_prep(
    const float* __restrict__ Wq, const float* __restrict__ Wk,
    const float* __restrict__ Wv, const float* __restrict__ Wp,
    bf16* __restrict__ Wb)
{
    const int idx = blockIdx.x * 256 + threadIdx.x;     // 65536 float4s total
    const int mat = idx >> 14;
    const float* src = (mat == 0) ? Wq : (mat == 1) ? Wk : (mat == 2) ? Wv : Wp;
    float4 v = reinterpret_cast<const float4*>(src)[idx & 16383];
    sh4 o;
    o[0] = f2bfs(v.x); o[1] = f2bfs(v.y); o[2] = f2bfs(v.z); o[3] = f2bfs(v.w);
    reinterpret_cast<sh4*>(reinterpret_cast<short*>(Wb))[idx] = o;
}

// ---------------------------------------------------------------------------
// K1: fused transpose + gates + q/k/v GEMM. 512 blocks = (b, 16 n-tile, mq).
// T-store XOR swizzle (16-way -> ~4-way LDS write conflicts);
// head-major qo/ko [b][h][n][32] so K2 stages dense 64B K rows.
// ---------------------------------------------------------------------------
__global__ __launch_bounds__(256) void k_fused5(
    const float* __restrict__ x, const float* __restrict__ gq, const float* __restrict__ gk,
    const float* __restrict__ Wsq, const float* __restrict__ bsq,
    const float* __restrict__ Wsk, const float* __restrict__ bsk,
    const bf16* __restrict__ Wb,
    const float* __restrict__ bq, const float* __restrict__ bk, const float* __restrict__ bv,
    bf16* __restrict__ qo, bf16* __restrict__ ko, bf16* __restrict__ vo,
    float* __restrict__ sqg)
{
    __shared__ short T[64 * TS];     // [pixel][c swizzled], 33.8 KB
    __shared__ float sq_lds[64];
    __shared__ float sk_lds[64];

    const int tid  = threadIdx.x;
    const int wave = tid >> 6;
    const int lane = tid & 63;
    const int col  = lane & 15;
    const int quad = lane >> 4;

    const int b    = blockIdx.x >> 6;
    const int rest = blockIdx.x & 63;
    const int n0   = (rest >> 2) * 64;   // 16 tiles of 64 px
    const int mq   = rest & 3;           // m-quarter (192 rows)

    // ---- stage x^T tile: 256 c-rows x 64 pixels (swizzled stores) ----
    {
        const float* xp = x + (size_t)b * C * N + n0;
        const int row = tid >> 4;        // 0..15 (c within pass)
        const int f   = tid & 15;        // float4 within 64 pixels
        const int sw  = (f & 7) << 3;    // tsw(4f+r) == (f&7)<<3 for r<4
#pragma unroll
        for (int p = 0; p < 16; ++p) {
            int c = p * 16 + row;
            float4 v = *reinterpret_cast<const float4*>(xp + (size_t)c * N + f * 4);
            int cs = c ^ sw;
            T[(f * 4 + 0) * TS + cs] = f2bfs(v.x);
            T[(f * 4 + 1) * TS + cs] = f2bfs(v.y);
            T[(f * 4 + 2) * TS + cs] = f2bfs(v.z);
            T[(f * 4 + 3) * TS + cs] = f2bfs(v.w);
        }
    }
    __syncthreads();

    // ---- gates (wave 0 only): logits via MFMA over 4 B-frags ----
    if (wave == 0) {
        const float* wsrc = (col < 4) ? (Wsq + col * C) : (Wsk + (col & 3) * C);
        f32x4 ga[4] = {};
#pragma unroll
        for (int k0 = 0; k0 < 256; k0 += 32) {
            float4 w0 = *reinterpret_cast<const float4*>(wsrc + k0 + quad * 8);
            float4 w1 = *reinterpret_cast<const float4*>(wsrc + k0 + quad * 8 + 4);
            short8 af = cvt8(w0, w1);
#pragma unroll
            for (int cf = 0; cf < 4; ++cf) {
                int px = cf * 16 + col;
                short8 bfr = *reinterpret_cast<const short8*>(
                    &T[px * TS + ((k0 + quad * 8) ^ tsw(px))]);
                ga[cf] = __builtin_amdgcn_mfma_f32_16x16x32_bf16(af, bfr, ga[cf], 0, 0, 0);
            }
        }
        if (quad < 2) {
            const float* bsrc = (quad == 0) ? bsq : bsk;
            const float* gsrc = (quad == 0) ? gq : gk;
#pragma unroll
            for (int cf = 0; cf < 4; ++cf) {
                int n = n0 + cf * 16 + col;
                float a[4];
#pragma unroll
                for (int r = 0; r < 4; ++r)
                    a[r] = ga[cf][r] + bsrc[r] + gsrc[(size_t)b * 4 * N + (size_t)r * N + n];
                float mx = fmaxf(fmaxf(a[0], a[1]), fmaxf(a[2], a[3]));
                float e = 0.f;
#pragma unroll
                for (int r = 0; r < 4; ++r) e += __expf(a[r] - mx);
                float p0 = __expf(a[0] - mx) / e;
                if (quad == 0) {
                    sq_lds[cf * 16 + col] = p0;
                    if (mq == 0) sqg[b * N + n] = p0;
                } else {
                    sk_lds[cf * 16 + col] = p0;
                }
            }
        }
    }
    __syncthreads();

    // ---- GEMM: this block's 192-row M quarter; 3 A-frags x 4 B-frags ----
    const short* Ws = reinterpret_cast<const short*>(Wb);
    const int mbase = mq * 192 + wave * 48;
    f32x4 acc[3][4] = {};
#pragma unroll
    for (int k0 = 0; k0 < 256; k0 += 32) {
        short8 bfr[4];
#pragma unroll
        for (int cf = 0; cf < 4; ++cf) {
            int px = cf * 16 + col;
            bfr[cf] = *reinterpret_cast<const short8*>(
                &T[px * TS + ((k0 + quad * 8) ^ tsw(px))]);
        }
#pragma unroll
        for (int i = 0; i < 3; ++i) {
            int m = mbase + i * 16;
            const short* wr = Ws + (size_t)(m >> 8) * 65536
                              + (size_t)((m & 255) + col) * 256 + k0 + quad * 8;
            short8 af = *reinterpret_cast<const short8*>(wr);
#pragma unroll
            for (int cf = 0; cf < 4; ++cf)
                acc[i][cf] = __builtin_amdgcn_mfma_f32_16x16x32_bf16(af, bfr[cf], acc[i][cf], 0, 0, 0);
        }
    }
    // epilogue (per-frag mat handles quarters spanning matrix boundaries)
#pragma unroll
    for (int i = 0; i < 3; ++i) {
        int m = mbase + i * 16;
        int mat = m >> 8;
        int cr  = (m & 255) + quad * 4;
        const float* bb = (mat == 0) ? bq : (mat == 1) ? bk : bv;
        float bias[4];
#pragma unroll
        for (int r = 0; r < 4; ++r) bias[r] = bb[cr + r];
        if (mat < 2) {
            // head-major [b][h][n][32]
            const int hh = cr >> 5, dd = cr & 31;
            short* op = reinterpret_cast<short*>((mat == 0) ? qo : ko)
                        + ((size_t)b * NH + hh) * N * HD + dd;
#pragma unroll
            for (int cf = 0; cf < 4; ++cf) {
                int n = n0 + cf * 16 + col;
                float g = (mat == 0) ? sq_lds[cf * 16 + col] * SCALE_E
                                     : sk_lds[cf * 16 + col];
                sh4 pack;
#pragma unroll
                for (int r = 0; r < 4; ++r) pack[r] = f2bfs((acc[i][cf][r] + bias[r]) * g);
                *reinterpret_cast<sh4*>(op + (size_t)n * HD) = pack;
            }
        } else {
            bf16* op = vo + (size_t)b * C * N;
#pragma unroll
            for (int cf = 0; cf < 4; ++cf) {
                int n = n0 + cf * 16 + col;
#pragma unroll
                for (int r = 0; r < 4; ++r)
                    op[(size_t)(cr + r) * N + n] = __float2bfloat16(acc[i][cf][r] + bias[r]);
            }
        }
    }
}

// ---------------------------------------------------------------------------
// K2: attention + gated mix, double-buffered K/V LDS staging (128-q tile,
// the structure measured at 31.4 us/pass in R4). Head-major qo/ko reads;
// exp2f softmax (log2e folded by K1). No XCD swizzle (unproven).
// ---------------------------------------------------------------------------
__global__ __launch_bounds__(256) void k_attn6(
    const bf16* __restrict__ qo, const bf16* __restrict__ ko,
    const bf16* __restrict__ vo, const float* __restrict__ sqg,
    bf16* __restrict__ gt)
{
    __shared__ short P_lds[4][32 * 72];   // 18.4 KB
    __shared__ short K_lds[2][64 * 40];   // 10.2 KB
    __shared__ short V_lds[2][32 * 72];   //  9.2 KB  (total 37.9 KB)

    const int tid  = threadIdx.x;
    const int wave = tid >> 6;
    const int lane = tid & 63;
    const int col  = lane & 15;
    const int quad = lane >> 4;

    const int b = blockIdx.x >> 6;
    const int h = (blockIdx.x >> 3) & 7;
    const int qbase = (blockIdx.x & 7) * 128 + wave * 32;

    const int skey = tid >> 2;          // 0..63
    const int sd   = (tid & 3) * 8;     // 0,8,16,24
    const int svd  = tid >> 3;          // 0..31
    const int svk  = (tid & 7) * 8;     // 0..56

    // head-major K/Q: [b][h][n][32]
    const short* kgp = reinterpret_cast<const short*>(ko) + ((size_t)b * NH + h) * N * HD;
    const short* qp0 = reinterpret_cast<const short*>(qo) + ((size_t)b * NH + h) * N * HD;
    const short* vgp = reinterpret_cast<const short*>(vo) + (size_t)b * C * N + (size_t)h * HD * N;
    const short* vp  = vgp;

    short8 qf[2];
#pragma unroll
    for (int g = 0; g < 2; ++g)
        qf[g] = *reinterpret_cast<const short8*>(
            qp0 + (size_t)(qbase + g * 16 + col) * HD + quad * 8);

    float l[2] = {};
    f32x4 oac[2][2] = {};   // [g][dh]
    short* P = P_lds[wave];

    short8 kstage = *reinterpret_cast<const short8*>(kgp + (size_t)skey * HD + sd);
    short8 vstage = *reinterpret_cast<const short8*>(vgp + (size_t)svd * N + svk);
    *reinterpret_cast<short8*>(&K_lds[0][skey * 40 + sd]) = kstage;
    *reinterpret_cast<short8*>(&V_lds[0][svd * 72 + svk]) = vstage;
    __syncthreads();

    for (int t = 0; t < 16; ++t) {
        const int tn = (t + 1) & 15;
        kstage = *reinterpret_cast<const short8*>(kgp + (size_t)(tn * 64 + skey) * HD + sd);
        vstage = *reinterpret_cast<const short8*>(vgp + (size_t)svd * N + tn * 64 + svk);

        const short* Kb = K_lds[t & 1];
        const short* Vb = V_lds[t & 1];

        short8 kf[4];
#pragma unroll
        for (int c = 0; c < 4; ++c)
            kf[c] = *reinterpret_cast<const short8*>(&Kb[(c * 16 + col) * 40 + quad * 8]);

#pragma unroll
        for (int g = 0; g < 2; ++g) {
            float s[16];
#pragma unroll
            for (int c = 0; c < 4; ++c) {
                f32x4 acc = {};
                acc = __builtin_amdgcn_mfma_f32_16x16x32_bf16(kf[c], qf[g], acc, 0, 0, 0);
#pragma unroll
                for (int r = 0; r < 4; ++r) s[c * 4 + r] = acc[r];
            }
            float p[16], lloc = 0.f;
#pragma unroll
            for (int i = 0; i < 16; ++i) { p[i] = exp2f(s[i]); lloc += p[i]; }
            lloc += __shfl_xor(lloc, 16, 64);
            lloc += __shfl_xor(lloc, 32, 64);
            l[g] += lloc;
#pragma unroll
            for (int c = 0; c < 4; ++c) {
                sh4 pk;
#pragma unroll
                for (int r = 0; r < 4; ++r) pk[r] = f2bfs(p[c * 4 + r]);
                *reinterpret_cast<sh4*>(&P[(g * 16 + col) * 72 + c * 16 + quad * 4]) = pk;
            }
        }

#pragma unroll
        for (int kg = 0; kg < 2; ++kg) {
            short8 vf[2];
#pragma unroll
            for (int dh = 0; dh < 2; ++dh)
                vf[dh] = *reinterpret_cast<const short8*>(&Vb[(dh * 16 + col) * 72 + kg * 32 + quad * 8]);
#pragma unroll
            for (int g = 0; g < 2; ++g) {
                short8 pf = *reinterpret_cast<const short8*>(&P[(g * 16 + col) * 72 + kg * 32 + quad * 8]);
#pragma unroll
                for (int dh = 0; dh < 2; ++dh)
                    oac[g][dh] = __builtin_amdgcn_mfma_f32_16x16x32_bf16(vf[dh], pf, oac[g][dh], 0, 0, 0);
            }
        }

        *reinterpret_cast<short8*>(&K_lds[(t + 1) & 1][skey * 40 + sd]) = kstage;
        *reinterpret_cast<short8*>(&V_lds[(t + 1) & 1][svd * 72 + svk]) = vstage;
        __syncthreads();
    }

    // epilogue: gated mix, pixel-major packed stores
#pragma unroll
    for (int g = 0; g < 2; ++g) {
        const int q = qbase + g * 16 + col;
        const float invl = 1.f / l[g];
        const float sqv  = sqg[b * N + q];
        const float hv   = 1.f - sqv;
        short* gp = reinterpret_cast<short*>(gt) + ((size_t)b * N + q) * C + h * HD + quad * 4;
#pragma unroll
        for (int dh = 0; dh < 2; ++dh) {
            sh4 pack;
#pragma unroll
            for (int r = 0; r < 4; ++r) {
                int d = dh * 16 + quad * 4 + r;
                float vb = bf2f(*reinterpret_cast<const bf16*>(vp + (size_t)d * N + q));
                pack[r] = f2bfs(sqv * (oac[g][dh][r] * invl) + hv * vb);
            }
            *reinterpret_cast<sh4*>(gp + dh * 16) = pack;
        }
    }
}

// ---------------------------------------------------------------------------
// K3: projection MFMA GEMM, 64m x 64n blocks with staged G tile (bf16 Wb).
// ---------------------------------------------------------------------------
__global__ __launch_bounds__(256) void k_projm5(
    const bf16* __restrict__ gt, const bf16* __restrict__ Wpb,
    const float* __restrict__ bp, float* __restrict__ out)
{
    __shared__ short G[64 * TS];   // [pixel][c], 33.8 KB

    const int tid  = threadIdx.x;
    const int wave = tid >> 6, lane = tid & 63;
    const int col  = lane & 15, quad = lane >> 4;
    const int mrow = blockIdx.x * 64 + wave * 16;    // wave owns 16 m rows
    const int b    = blockIdx.z;
    const int n0   = blockIdx.y * 64;

    // ---- stage gt tile: 64 pixels x 256 c (no transpose, no convert) ----
    {
        const short* gp = reinterpret_cast<const short*>(gt) + ((size_t)b * N + n0) * C;
        const int px = tid >> 2;          // 0..63
        const int c0 = (tid & 3) * 64;    // 0,64,128,192
#pragma unroll
        for (int j = 0; j < 8; ++j) {
            short8 v = *reinterpret_cast<const short8*>(gp + (size_t)px * C + c0 + j * 8);
            *reinterpret_cast<short8*>(&G[px * TS + c0 + j * 8]) = v;
        }
    }
    __syncthreads();

    const short* Wm = reinterpret_cast<const short*>(Wpb);

    f32x4 acc[4] = {};   // [nfrag]
#pragma unroll
    for (int k0 = 0; k0 < 256; k0 += 32) {
        short8 af = *reinterpret_cast<const short8*>(Wm + (size_t)(mrow + col) * 256 + k0 + quad * 8);
#pragma unroll
        for (int cf = 0; cf < 4; ++cf) {
            short8 bfr = *reinterpret_cast<const short8*>(&G[(cf * 16 + col) * TS + k0 + quad * 8]);
            acc[cf] = __builtin_amdgcn_mfma_f32_16x16x32_bf16(af, bfr, acc[cf], 0, 0, 0);
        }
    }

    const int cr = mrow + quad * 4;
    float bias[4];
#pragma unroll
    for (int r = 0; r < 4; ++r) bias[r] = bp[cr + r];
    float* op = out + (size_t)b * C * N;
#pragma unroll
    for (int cf = 0; cf < 4; ++cf) {
        int n = n0 + cf * 16 + col;
#pragma unroll
        for (int r = 0; r < 4; ++r)
            op[(size_t)(cr + r) * N + n] = acc[cf][r] + bias[r];
    }
}

// ---------------------------------------------------------------------------
// Workspace (bytes):
//   [0, 32K)        sqg f32 [8][1024]
//   [32K, 544K)     Wb bf16 [4][256][256]  (q,k,v,p)
//   [544K, +4M)     qo bf16 [8][8][1024][32] (head-major, sq*SCALE*log2e folded)
//   +4M             ko bf16 [8][8][1024][32] (head-major, sk folded)
//   +4M             vo bf16 [8][256][1024]   (d-major)
//   +4M             gt bf16 [8][1024][256]   (gated rows, pixel-major)
// ---------------------------------------------------------------------------
extern "C" void kernel_launch(void* const* d_in, const int* in_sizes, int n_in,
                              void* d_out, int out_size, void* d_ws, size_t ws_size,
                              hipStream_t stream)
{
    const float* x   = (const float*)d_in[0];
    const float* gq  = (const float*)d_in[1];
    const float* gk  = (const float*)d_in[2];
    const float* Wsq = (const float*)d_in[3];
    const float* bsq = (const float*)d_in[4];
    const float* Wsk = (const float*)d_in[5];
    const float* bsk = (const float*)d_in[6];
    const float* Wq  = (const float*)d_in[7];
    const float* bq  = (const float*)d_in[8];
    const float* Wk  = (const float*)d_in[9];
    const float* bk  = (const float*)d_in[10];
    const float* Wv  = (const float*)d_in[11];
    const float* bv  = (const float*)d_in[12];
    const float* Wp  = (const float*)d_in[13];
    const float* bp  = (const float*)d_in[14];

    char* ws = (char*)d_ws;
    float* sqg = (float*)ws;
    bf16* Wb   = (bf16*)(ws + 32768);
    bf16* qo   = (bf16*)(ws + 32768 + 524288);
    bf16* ko   = qo + (size_t)Bn * N * C;
    bf16* vo   = ko + (size_t)Bn * N * C;
    bf16* gt   = vo + (size_t)Bn * C * N;
    float* out = (float*)d_out;

    k_prep<<<256, 256, 0, stream>>>(Wq, Wk, Wv, Wp, Wb);
    k_fused5<<<512, 256, 0, stream>>>(x, gq, gk, Wsq, bsq, Wsk, bsk,
                                      Wb, bq, bk, bv, qo, ko, vo, sqg);
    k_attn6<<<512, 256, 0, stream>>>(qo, ko, vo, sqg, gt);
    k_projm5<<<dim3(4, 16, 8), 256, 0, stream>>>(gt, Wb + 3 * 65536, bp, out);
}